// Round 1
// baseline (853.623 us; speedup 1.0000x reference)
//
#include <hip/hip_runtime.h>
#include <math.h>

#define Nn 4096
#define Gd 512
#define Hd 256
#define PW 768   // packed operand width: 256 (Q or K) + 512 (normalized gene)

__device__ inline float tanh_fast(float x) {
    x = fminf(fmaxf(x, -15.f), 15.f);
    float e2 = __expf(2.f * x);
    return (e2 - 1.f) / (e2 + 1.f);
}

// ---------------------------------------------------------------- k_norm
// per-node: 1/max(||gene_row||,1e-12) and |p|^2.  1 wave per node.
__global__ __launch_bounds__(64) void k_norm(const float* __restrict__ gene,
                                             const float* __restrict__ pos,
                                             float* __restrict__ rinvb,
                                             float* __restrict__ sqbuf) {
    int i = blockIdx.x, t = threadIdx.x;
    const float4* gr = (const float4*)(gene + (size_t)i * Gd);  // 128 float4
    float4 a = gr[t], b = gr[t + 64];
    float ss = a.x*a.x + a.y*a.y + a.z*a.z + a.w*a.w
             + b.x*b.x + b.y*b.y + b.z*b.z + b.w*b.w;
    #pragma unroll
    for (int m = 1; m < 64; m <<= 1) ss += __shfl_xor(ss, m, 64);
    if (t == 0) {
        rinvb[i] = 1.f / fmaxf(sqrtf(ss), 1e-12f);
        float p0 = pos[2*i], p1 = pos[2*i+1];
        sqbuf[i] = p0*p0 + p1*p1;
    }
}

// ---------------------------------------------------------------- k_mlp
// spatial MLP -> f[i].  16 nodes per block so W1/W2 column reads amortize.
__global__ __launch_bounds__(256) void k_mlp(const float* __restrict__ pos,
                                             const float* __restrict__ Ws, const float* __restrict__ bs,
                                             const float* __restrict__ W1, const float* __restrict__ b1,
                                             const float* __restrict__ W2, const float* __restrict__ b2,
                                             const float* __restrict__ Wf, const float* __restrict__ bf,
                                             float* __restrict__ fbuf) {
    __shared__ float s_a[16][Hd];   // si, later e
    __shared__ float s_h[16][Hd];   // tanh hidden
    __shared__ float sp[32];
    __shared__ float red[256];
    int t = threadIdx.x;
    int i0 = blockIdx.x * 16;
    if (t < 32) sp[t] = pos[i0 * 2 + t];
    __syncthreads();
    float ws0 = Ws[t], ws1 = Ws[Hd + t], bsv = bs[t];
    #pragma unroll
    for (int n = 0; n < 16; ++n)
        s_a[n][t] = sp[2*n] * ws0 + sp[2*n+1] * ws1 + bsv;
    __syncthreads();
    // h = tanh(si @ W1 + b1)
    float accs[16];
    #pragma unroll
    for (int n = 0; n < 16; ++n) accs[n] = 0.f;
    for (int k = 0; k < Hd; ++k) {
        float w = W1[k * Hd + t];
        #pragma unroll
        for (int n = 0; n < 16; ++n) accs[n] += s_a[n][k] * w;
    }
    float b1v = b1[t];
    #pragma unroll
    for (int n = 0; n < 16; ++n) s_h[n][t] = tanh_fast(accs[n] + b1v);
    __syncthreads();
    // e = relu(h @ W2 + b2)  (overwrites s_a)
    #pragma unroll
    for (int n = 0; n < 16; ++n) accs[n] = 0.f;
    for (int k = 0; k < Hd; ++k) {
        float w = W2[k * Hd + t];
        #pragma unroll
        for (int n = 0; n < 16; ++n) accs[n] += s_h[n][k] * w;
    }
    float b2v = b2[t];
    __syncthreads();
    #pragma unroll
    for (int n = 0; n < 16; ++n) s_a[n][t] = fmaxf(accs[n] + b2v, 0.f);
    __syncthreads();
    // f = e . Wf + bf   (16 tree reductions)
    float wf = Wf[t];
    for (int n = 0; n < 16; ++n) {
        red[t] = s_a[n][t] * wf;
        __syncthreads();
        for (int s = 128; s > 0; s >>= 1) {
            if (t < s) red[t] += red[t + s];
            __syncthreads();
        }
        if (t == 0) fbuf[i0 + n] = red[0] + bf[0];
        __syncthreads();
    }
}

// ---------------------------------------------------------------- k_qkv
// [4096,512] @ [512,768] (Wq|Wk|Wv).  BM=BN=128, BK=8, 8x8 acc/thread.
// by: 0,1 -> Q (scaled 1/16, into packA) ; 2,3 -> K (packB) ; 4,5 -> V.
__global__ __launch_bounds__(256) void k_qkv(const float* __restrict__ gene,
                                             const float* __restrict__ Wq, const float* __restrict__ bq,
                                             const float* __restrict__ Wk, const float* __restrict__ bk,
                                             const float* __restrict__ Wv, const float* __restrict__ bv,
                                             float* __restrict__ packA, float* __restrict__ packB,
                                             float* __restrict__ Vbuf) {
    __shared__ float As[8][132];   // transposed: As[k][m]
    __shared__ float Bs[8][132];
    int t = threadIdx.x;
    int tx = t & 15, ty = t >> 4;
    int rb = blockIdx.x * 128;
    int mid = blockIdx.y >> 1;                  // 0=Q 1=K 2=V
    int cbase = (blockIdx.y & 1) * 128;
    const float* Wm  = (mid == 0) ? Wq : (mid == 1) ? Wk : Wv;
    const float* bia = (mid == 0) ? bq : (mid == 1) ? bk : bv;

    float acc[8][8];
    #pragma unroll
    for (int m = 0; m < 8; ++m)
        #pragma unroll
        for (int n = 0; n < 8; ++n) acc[m][n] = 0.f;

    for (int kt = 0; kt < Gd; kt += 8) {
        {   // A tile 128x8
            int row = t >> 1, seg = t & 1;
            float4 a = *(const float4*)(gene + (size_t)(rb + row) * Gd + kt + seg * 4);
            As[seg*4+0][row] = a.x; As[seg*4+1][row] = a.y;
            As[seg*4+2][row] = a.z; As[seg*4+3][row] = a.w;
            // B tile 8x128
            int brow = t >> 5, bcol = (t & 31) * 4;
            *(float4*)&Bs[brow][bcol] =
                *(const float4*)(Wm + (size_t)(kt + brow) * Hd + cbase + bcol);
        }
        __syncthreads();
        #pragma unroll
        for (int kk = 0; kk < 8; ++kk) {
            float4 a0 = *(const float4*)&As[kk][ty*8];
            float4 a1 = *(const float4*)&As[kk][ty*8+4];
            float4 b0 = *(const float4*)&Bs[kk][tx*8];
            float4 b1 = *(const float4*)&Bs[kk][tx*8+4];
            float av[8] = {a0.x,a0.y,a0.z,a0.w,a1.x,a1.y,a1.z,a1.w};
            float bvv[8] = {b0.x,b0.y,b0.z,b0.w,b1.x,b1.y,b1.z,b1.w};
            #pragma unroll
            for (int m = 0; m < 8; ++m)
                #pragma unroll
                for (int n = 0; n < 8; ++n) acc[m][n] += av[m] * bvv[n];
        }
        __syncthreads();
    }
    float scale = (mid == 0) ? 0.0625f : 1.f;
    float* dst  = (mid == 0) ? packA : (mid == 1) ? packB : Vbuf;
    int stride  = (mid == 2) ? Hd : PW;
    int c0 = cbase + tx * 8;
    #pragma unroll
    for (int m = 0; m < 8; ++m) {
        int r = rb + ty * 8 + m;
        float4 o0, o1;
        o0.x = (acc[m][0] + bia[c0+0]) * scale;
        o0.y = (acc[m][1] + bia[c0+1]) * scale;
        o0.z = (acc[m][2] + bia[c0+2]) * scale;
        o0.w = (acc[m][3] + bia[c0+3]) * scale;
        o1.x = (acc[m][4] + bia[c0+4]) * scale;
        o1.y = (acc[m][5] + bia[c0+5]) * scale;
        o1.z = (acc[m][6] + bia[c0+6]) * scale;
        o1.w = (acc[m][7] + bia[c0+7]) * scale;
        *(float4*)(dst + (size_t)r * stride + c0)     = o0;
        *(float4*)(dst + (size_t)r * stride + c0 + 4) = o1;
    }
}

// ---------------------------------------------------------------- k_pack
// normalized gene rows into cols [256,768) of packA and packB
__global__ __launch_bounds__(256) void k_pack(const float* __restrict__ gene,
                                              const float* __restrict__ rinvb,
                                              float* __restrict__ packA, float* __restrict__ packB) {
    int id = blockIdx.x * 256 + threadIdx.x;      // one float4 each, 524288 total
    int row = id >> 7;
    int c4 = (id & 127) << 2;
    float ri = rinvb[row];
    float4 v = *(const float4*)(gene + (size_t)row * Gd + c4);
    v.x *= ri; v.y *= ri; v.z *= ri; v.w *= ri;
    *(float4*)(packA + (size_t)row * PW + Hd + c4) = v;
    *(float4*)(packB + (size_t)row * PW + Hd + c4) = v;
}

// ---------------------------------------------------------------- k_logits
// S = packA @ packB^T + exp(-d2/2) + tanh(fi-fj).  128x128x16, 8x8/thread.
__global__ __launch_bounds__(256) void k_logits(const float* __restrict__ packA,
                                                const float* __restrict__ packB,
                                                const float* __restrict__ pos,
                                                const float* __restrict__ fbuf,
                                                const float* __restrict__ sqbuf,
                                                float* __restrict__ S) {
    __shared__ float As[16][136];   // [k][m]
    __shared__ float Bs[16][136];   // [k][n]
    int t = threadIdx.x;
    int tx = t & 15, ty = t >> 4;
    int rb = blockIdx.x * 128;
    int cb = blockIdx.y * 128;

    float acc[8][8];
    #pragma unroll
    for (int m = 0; m < 8; ++m)
        #pragma unroll
        for (int n = 0; n < 8; ++n) acc[m][n] = 0.f;

    for (int kt = 0; kt < PW; kt += 16) {
        #pragma unroll
        for (int li = 0; li < 2; ++li) {
            int idx = t + li * 256;
            int row = idx >> 2, seg = idx & 3;
            float4 a = *(const float4*)(packA + (size_t)(rb + row) * PW + kt + seg * 4);
            float4 b = *(const float4*)(packB + (size_t)(cb + row) * PW + kt + seg * 4);
            As[seg*4+0][row] = a.x; As[seg*4+1][row] = a.y;
            As[seg*4+2][row] = a.z; As[seg*4+3][row] = a.w;
            Bs[seg*4+0][row] = b.x; Bs[seg*4+1][row] = b.y;
            Bs[seg*4+2][row] = b.z; Bs[seg*4+3][row] = b.w;
        }
        __syncthreads();
        #pragma unroll
        for (int kk = 0; kk < 16; ++kk) {
            float4 a0 = *(const float4*)&As[kk][ty*8];
            float4 a1 = *(const float4*)&As[kk][ty*8+4];
            float4 b0 = *(const float4*)&Bs[kk][tx*8];
            float4 b1 = *(const float4*)&Bs[kk][tx*8+4];
            float av[8] = {a0.x,a0.y,a0.z,a0.w,a1.x,a1.y,a1.z,a1.w};
            float bvv[8] = {b0.x,b0.y,b0.z,b0.w,b1.x,b1.y,b1.z,b1.w};
            #pragma unroll
            for (int m = 0; m < 8; ++m)
                #pragma unroll
                for (int n = 0; n < 8; ++n) acc[m][n] += av[m] * bvv[n];
        }
        __syncthreads();
    }
    // epilogue: + gaussian spatial sim + tanh bias
    float fj[8], sqj[8], pj0[8], pj1[8];
    #pragma unroll
    for (int n = 0; n < 8; ++n) {
        int c = cb + tx * 8 + n;
        fj[n] = fbuf[c]; sqj[n] = sqbuf[c];
        pj0[n] = pos[2*c]; pj1[n] = pos[2*c+1];
    }
    #pragma unroll
    for (int m = 0; m < 8; ++m) {
        int r = rb + ty * 8 + m;
        float fi = fbuf[r], sqi = sqbuf[r];
        float pi0 = pos[2*r], pi1 = pos[2*r+1];
        float out[8];
        #pragma unroll
        for (int n = 0; n < 8; ++n) {
            float d2 = fmaxf(sqi + sqj[n] - 2.f * (pi0 * pj0[n] + pi1 * pj1[n]), 0.f);
            out[n] = acc[m][n] + __expf(-0.5f * d2) + tanh_fast(fi - fj[n]);
        }
        float4 o0 = {out[0], out[1], out[2], out[3]};
        float4 o1 = {out[4], out[5], out[6], out[7]};
        *(float4*)(S + (size_t)r * Nn + cb + tx * 8)     = o0;
        *(float4*)(S + (size_t)r * Nn + cb + tx * 8 + 4) = o1;
    }
}

// ---------------------------------------------------------------- k_rowstats
// per-row max and 1/sum(exp(x-max)).  1 block per row.
__global__ __launch_bounds__(256) void k_rowstats(const float* __restrict__ S,
                                                  float* __restrict__ mbuf,
                                                  float* __restrict__ lbuf) {
    int r = blockIdx.x, t = threadIdx.x;
    const float4* row = (const float4*)(S + (size_t)r * Nn);
    float4 v0 = row[t], v1 = row[t + 256], v2 = row[t + 512], v3 = row[t + 768];
    __shared__ float red[256];
    float mx = fmaxf(fmaxf(fmaxf(v0.x, v0.y), fmaxf(v0.z, v0.w)),
               fmaxf(fmaxf(fmaxf(v1.x, v1.y), fmaxf(v1.z, v1.w)),
               fmaxf(fmaxf(fmaxf(v2.x, v2.y), fmaxf(v2.z, v2.w)),
                     fmaxf(fmaxf(v3.x, v3.y), fmaxf(v3.z, v3.w)))));
    red[t] = mx;
    __syncthreads();
    for (int s = 128; s > 0; s >>= 1) {
        if (t < s) red[t] = fmaxf(red[t], red[t + s]);
        __syncthreads();
    }
    mx = red[0];
    __syncthreads();
    float sum = __expf(v0.x - mx) + __expf(v0.y - mx) + __expf(v0.z - mx) + __expf(v0.w - mx)
              + __expf(v1.x - mx) + __expf(v1.y - mx) + __expf(v1.z - mx) + __expf(v1.w - mx)
              + __expf(v2.x - mx) + __expf(v2.y - mx) + __expf(v2.z - mx) + __expf(v2.w - mx)
              + __expf(v3.x - mx) + __expf(v3.y - mx) + __expf(v3.z - mx) + __expf(v3.w - mx);
    red[t] = sum;
    __syncthreads();
    for (int s = 128; s > 0; s >>= 1) {
        if (t < s) red[t] += red[t + s];
        __syncthreads();
    }
    if (t == 0) { mbuf[r] = mx; lbuf[r] = 1.f / red[0]; }
}

// ---------------------------------------------------------------- k_av
// normalize logits in place -> attention weights, and O = A @ V.
// 16 rows/block, k-tile 32, V staged in LDS.
__global__ __launch_bounds__(256) void k_av(float* __restrict__ S,
                                            const float* __restrict__ mbuf,
                                            const float* __restrict__ lbuf,
                                            const float* __restrict__ Vbuf,
                                            float* __restrict__ Oout) {
    __shared__ float As[16][33];
    __shared__ float Vs[32][256];
    __shared__ float sm[16], sl[16];
    int t = threadIdx.x;
    int tx = t & 31, ty = t >> 5;
    int rb = blockIdx.x * 16;
    if (t < 16) { sm[t] = mbuf[rb + t]; sl[t] = lbuf[rb + t]; }
    float acc[2][8];
    #pragma unroll
    for (int rr = 0; rr < 2; ++rr)
        #pragma unroll
        for (int n = 0; n < 8; ++n) acc[rr][n] = 0.f;
    __syncthreads();

    for (int jt = 0; jt < Nn; jt += 32) {
        if (t < 128) {
            int row = t >> 3, seg = t & 7;
            size_t off = (size_t)(rb + row) * Nn + jt + seg * 4;
            float4 x = *(const float4*)(S + off);
            float mr = sm[row], lr = sl[row];
            float4 w;
            w.x = __expf(x.x - mr) * lr;
            w.y = __expf(x.y - mr) * lr;
            w.z = __expf(x.z - mr) * lr;
            w.w = __expf(x.w - mr) * lr;
            *(float4*)(S + off) = w;
            As[row][seg*4+0] = w.x; As[row][seg*4+1] = w.y;
            As[row][seg*4+2] = w.z; As[row][seg*4+3] = w.w;
        }
        #pragma unroll
        for (int q = 0; q < 8; ++q) {
            int idx = t + q * 256;
            int vr = idx >> 6, c4 = (idx & 63) << 2;
            *(float4*)&Vs[vr][c4] = *(const float4*)(Vbuf + (size_t)(jt + vr) * Hd + c4);
        }
        __syncthreads();
        #pragma unroll
        for (int kk = 0; kk < 32; ++kk) {
            float a0 = As[ty*2][kk], a1 = As[ty*2+1][kk];
            float4 b0 = *(const float4*)&Vs[kk][tx*8];
            float4 b1 = *(const float4*)&Vs[kk][tx*8+4];
            acc[0][0] += a0*b0.x; acc[0][1] += a0*b0.y; acc[0][2] += a0*b0.z; acc[0][3] += a0*b0.w;
            acc[0][4] += a0*b1.x; acc[0][5] += a0*b1.y; acc[0][6] += a0*b1.z; acc[0][7] += a0*b1.w;
            acc[1][0] += a1*b0.x; acc[1][1] += a1*b0.y; acc[1][2] += a1*b0.z; acc[1][3] += a1*b0.w;
            acc[1][4] += a1*b1.x; acc[1][5] += a1*b1.y; acc[1][6] += a1*b1.z; acc[1][7] += a1*b1.w;
        }
        __syncthreads();
    }
    #pragma unroll
    for (int rr = 0; rr < 2; ++rr) {
        int r = rb + ty * 2 + rr;
        float4 o0 = {acc[rr][0], acc[rr][1], acc[rr][2], acc[rr][3]};
        float4 o1 = {acc[rr][4], acc[rr][5], acc[rr][6], acc[rr][7]};
        *(float4*)(Oout + (size_t)r * Hd + tx * 8)     = o0;
        *(float4*)(Oout + (size_t)r * Hd + tx * 8 + 4) = o1;
    }
}

// ---------------------------------------------------------------- launch
extern "C" void kernel_launch(void* const* d_in, const int* in_sizes, int n_in,
                              void* d_out, int out_size, void* d_ws, size_t ws_size,
                              hipStream_t stream) {
    const float* gene = (const float*)d_in[0];
    const float* pos  = (const float*)d_in[1];
    const float* Wq = (const float*)d_in[2];  const float* bq = (const float*)d_in[3];
    const float* Wk = (const float*)d_in[4];  const float* bk = (const float*)d_in[5];
    const float* Wv = (const float*)d_in[6];  const float* bv = (const float*)d_in[7];
    const float* Ws = (const float*)d_in[8];  const float* bs = (const float*)d_in[9];
    const float* W1 = (const float*)d_in[10]; const float* b1 = (const float*)d_in[11];
    const float* W2 = (const float*)d_in[12]; const float* b2 = (const float*)d_in[13];
    const float* Wf = (const float*)d_in[14]; const float* bf = (const float*)d_in[15];

    float* ws    = (float*)d_ws;
    float* packA = ws;                             // [N][768]  (Q/16 | xn)
    float* packB = packA + (size_t)Nn * PW;        // [N][768]  (K    | xn)
    float* Vbuf  = packB + (size_t)Nn * PW;        // [N][256]
    float* fbuf  = Vbuf + (size_t)Nn * Hd;         // [N]
    float* sqbuf = fbuf + Nn;                      // [N]
    float* rinvb = sqbuf + Nn;                     // [N]
    float* mbuf  = rinvb + Nn;                     // [N]
    float* lbuf  = mbuf + Nn;                      // [N]

    float* S = (float*)d_out;                      // [N][N] attention weights
    float* O = S + (size_t)Nn * Nn;                // [N][256]

    k_norm<<<Nn, 64, 0, stream>>>(gene, pos, rinvb, sqbuf);
    k_mlp<<<Nn / 16, 256, 0, stream>>>(pos, Ws, bs, W1, b1, W2, b2, Wf, bf, fbuf);
    k_qkv<<<dim3(Nn / 128, 6), 256, 0, stream>>>(gene, Wq, bq, Wk, bk, Wv, bv,
                                                 packA, packB, Vbuf);
    k_pack<<<(Nn * (Gd / 4)) / 256, 256, 0, stream>>>(gene, rinvb, packA, packB);
    k_logits<<<dim3(Nn / 128, Nn / 128), 256, 0, stream>>>(packA, packB, pos,
                                                           fbuf, sqbuf, S);
    k_rowstats<<<Nn, 256, 0, stream>>>(S, mbuf, lbuf);
    k_av<<<Nn / 16, 256, 0, stream>>>(S, mbuf, lbuf, Vbuf, O);
}

// Round 5
// 344.341 us; speedup vs baseline: 2.4790x; 2.4790x over previous
//
#include <hip/hip_runtime.h>

#define Nn 4096
#define Gd 512
#define Hd 256
#define PW 768   // packed operand width: 256 (Q or K) + 512 (normalized gene)

typedef float f32x4 __attribute__((ext_vector_type(4)));
typedef short s16x8 __attribute__((ext_vector_type(8)));
typedef unsigned short u16x4v __attribute__((ext_vector_type(4)));
typedef unsigned short u16x8v __attribute__((ext_vector_type(8)));

// async global->LDS, 16B per lane; LDS dest must be wave-uniform base + lane*16.
#define GLL(gp, lp) __builtin_amdgcn_global_load_lds((const __attribute__((address_space(1))) void*)(gp), (__attribute__((address_space(3))) void*)(lp), 16, 0, 0)

// fp32 -> bf16 bits, round-to-nearest-even (integer path; no __bf16 types)
__device__ inline unsigned short f2bf(float x) {
    unsigned u = __builtin_bit_cast(unsigned, x);
    return (unsigned short)((u + 0x7FFFu + ((u >> 16) & 1u)) >> 16);
}

__device__ inline float tanh_fast(float x) {
    x = __builtin_fminf(__builtin_fmaxf(x, -15.f), 15.f);
    float e2 = __expf(2.f * x);
    return (e2 - 1.f) / (e2 + 1.f);
}

// ---------------------------------------------------------------- k_norm
__global__ __launch_bounds__(64) void k_norm(const float* __restrict__ gene,
                                             const float* __restrict__ pos,
                                             float* __restrict__ rinvb,
                                             float* __restrict__ sqbuf) {
    int i = blockIdx.x, t = threadIdx.x;
    const float4* gr = (const float4*)(gene + (size_t)i * Gd);
    float4 a = gr[t], b = gr[t + 64];
    float ss = a.x*a.x + a.y*a.y + a.z*a.z + a.w*a.w
             + b.x*b.x + b.y*b.y + b.z*b.z + b.w*b.w;
    #pragma unroll
    for (int m = 1; m < 64; m <<= 1) ss += __shfl_xor(ss, m, 64);
    if (t == 0) {
        rinvb[i] = 1.f / __builtin_fmaxf(__builtin_sqrtf(ss), 1e-12f);
        float p0 = pos[2*i], p1 = pos[2*i+1];
        sqbuf[i] = p0*p0 + p1*p1;
    }
}

// ---------------------------------------------------------------- k_mlp
__global__ __launch_bounds__(256) void k_mlp(const float* __restrict__ pos,
                                             const float* __restrict__ Ws, const float* __restrict__ bs,
                                             const float* __restrict__ W1, const float* __restrict__ b1,
                                             const float* __restrict__ W2, const float* __restrict__ b2,
                                             const float* __restrict__ Wf, const float* __restrict__ bf,
                                             float* __restrict__ fbuf) {
    __shared__ float s_a[16][Hd];
    __shared__ float s_h[16][Hd];
    __shared__ float sp[32];
    __shared__ float red[256];
    int t = threadIdx.x;
    int i0 = blockIdx.x * 16;
    if (t < 32) sp[t] = pos[i0 * 2 + t];
    __syncthreads();
    float ws0 = Ws[t], ws1 = Ws[Hd + t], bsv = bs[t];
    #pragma unroll
    for (int n = 0; n < 16; ++n)
        s_a[n][t] = sp[2*n] * ws0 + sp[2*n+1] * ws1 + bsv;
    __syncthreads();
    float accs[16];
    #pragma unroll
    for (int n = 0; n < 16; ++n) accs[n] = 0.f;
    for (int k = 0; k < Hd; ++k) {
        float w = W1[k * Hd + t];
        #pragma unroll
        for (int n = 0; n < 16; ++n) accs[n] += s_a[n][k] * w;
    }
    float b1v = b1[t];
    #pragma unroll
    for (int n = 0; n < 16; ++n) s_h[n][t] = tanh_fast(accs[n] + b1v);
    __syncthreads();
    #pragma unroll
    for (int n = 0; n < 16; ++n) accs[n] = 0.f;
    for (int k = 0; k < Hd; ++k) {
        float w = W2[k * Hd + t];
        #pragma unroll
        for (int n = 0; n < 16; ++n) accs[n] += s_h[n][k] * w;
    }
    float b2v = b2[t];
    __syncthreads();
    #pragma unroll
    for (int n = 0; n < 16; ++n) s_a[n][t] = __builtin_fmaxf(accs[n] + b2v, 0.f);
    __syncthreads();
    float wf = Wf[t];
    for (int n = 0; n < 16; ++n) {
        red[t] = s_a[n][t] * wf;
        __syncthreads();
        for (int s = 128; s > 0; s >>= 1) {
            if (t < s) red[t] += red[t + s];
            __syncthreads();
        }
        if (t == 0) fbuf[i0 + n] = red[0] + bf[0];
        __syncthreads();
    }
}

// ---------------------------------------------------------------- k_qkv
// [4096,512] @ [512,768].  fp32 compute; bf16-bit (ushort) outputs:
// mid 0 -> packA (Q/16), mid 1 -> packB (K), mid 2 -> Vt (transposed [256][4096]).
__global__ __launch_bounds__(256) void k_qkv(const float* __restrict__ gene,
                                             const float* __restrict__ Wq, const float* __restrict__ bq,
                                             const float* __restrict__ Wk, const float* __restrict__ bk,
                                             const float* __restrict__ Wv, const float* __restrict__ bv,
                                             unsigned short* __restrict__ packA,
                                             unsigned short* __restrict__ packB,
                                             unsigned short* __restrict__ Vt) {
    __shared__ float As[8][132];
    __shared__ float Bs[8][132];
    int t = threadIdx.x;
    int tx = t & 15, ty = t >> 4;
    int rb = blockIdx.x * 128;
    int mid = blockIdx.y >> 1;                  // 0=Q 1=K 2=V
    int cbase = (blockIdx.y & 1) * 128;
    const float* Wm  = (mid == 0) ? Wq : (mid == 1) ? Wk : Wv;
    const float* bia = (mid == 0) ? bq : (mid == 1) ? bk : bv;

    float acc[8][8];
    #pragma unroll
    for (int m = 0; m < 8; ++m)
        #pragma unroll
        for (int n = 0; n < 8; ++n) acc[m][n] = 0.f;

    for (int kt = 0; kt < Gd; kt += 8) {
        {
            int row = t >> 1, seg = t & 1;
            float4 a = *(const float4*)(gene + (size_t)(rb + row) * Gd + kt + seg * 4);
            As[seg*4+0][row] = a.x; As[seg*4+1][row] = a.y;
            As[seg*4+2][row] = a.z; As[seg*4+3][row] = a.w;
            int brow = t >> 5, bcol = (t & 31) * 4;
            *(float4*)&Bs[brow][bcol] =
                *(const float4*)(Wm + (size_t)(kt + brow) * Hd + cbase + bcol);
        }
        __syncthreads();
        #pragma unroll
        for (int kk = 0; kk < 8; ++kk) {
            float4 a0 = *(const float4*)&As[kk][ty*8];
            float4 a1 = *(const float4*)&As[kk][ty*8+4];
            float4 b0 = *(const float4*)&Bs[kk][tx*8];
            float4 b1 = *(const float4*)&Bs[kk][tx*8+4];
            float av[8] = {a0.x,a0.y,a0.z,a0.w,a1.x,a1.y,a1.z,a1.w};
            float bvv[8] = {b0.x,b0.y,b0.z,b0.w,b1.x,b1.y,b1.z,b1.w};
            #pragma unroll
            for (int m = 0; m < 8; ++m)
                #pragma unroll
                for (int n = 0; n < 8; ++n) acc[m][n] += av[m] * bvv[n];
        }
        __syncthreads();
    }
    int c0 = cbase + tx * 8;
    if (mid == 2) {
        // Vt[c][r]: for fixed col, 8 consecutive rows -> one 16B store
        #pragma unroll
        for (int n = 0; n < 8; ++n) {
            int c = c0 + n;
            float bb = bia[c];
            u16x8v o;
            #pragma unroll
            for (int m = 0; m < 8; ++m) o[m] = f2bf(acc[m][n] + bb);
            *(u16x8v*)(Vt + (size_t)c * Nn + rb + ty * 8) = o;
        }
    } else {
        unsigned short* dst = (mid == 0) ? packA : packB;
        float scale = (mid == 0) ? 0.0625f : 1.f;
        #pragma unroll
        for (int m = 0; m < 8; ++m) {
            int r = rb + ty * 8 + m;
            u16x8v o;
            #pragma unroll
            for (int n = 0; n < 8; ++n) o[n] = f2bf((acc[m][n] + bia[c0+n]) * scale);
            *(u16x8v*)(dst + (size_t)r * PW + c0) = o;
        }
    }
}

// ---------------------------------------------------------------- k_pack
// normalized gene rows (bf16 bits) into cols [256,768) of packA and packB
__global__ __launch_bounds__(256) void k_pack(const float* __restrict__ gene,
                                              const float* __restrict__ rinvb,
                                              unsigned short* __restrict__ packA,
                                              unsigned short* __restrict__ packB) {
    int id = blockIdx.x * 256 + threadIdx.x;      // 4096*128 float4s
    int row = id >> 7;
    int c4 = (id & 127) << 2;
    float ri = rinvb[row];
    float4 v = *(const float4*)(gene + (size_t)row * Gd + c4);
    u16x4v b;
    b[0] = f2bf(v.x * ri); b[1] = f2bf(v.y * ri);
    b[2] = f2bf(v.z * ri); b[3] = f2bf(v.w * ri);
    *(u16x4v*)(packA + (size_t)row * PW + Hd + c4) = b;
    *(u16x4v*)(packB + (size_t)row * PW + Hd + c4) = b;
}

// ---------------------------------------------------------------- k_logits
// S = packA @ packB^T (bf16 MFMA, fp32 acc) + exp(-d2/2) + tanh(fi-fj).
// 128x128 tile, BK=32, 4 waves (2x2), each wave 64x64 = 4x4 frags 16x16x32.
__global__ __launch_bounds__(256) void k_logits(const unsigned short* __restrict__ packA,
                                                const unsigned short* __restrict__ packB,
                                                const float* __restrict__ pos,
                                                const float* __restrict__ fbuf,
                                                const float* __restrict__ sqbuf,
                                                float* __restrict__ S) {
    __shared__ unsigned short As[128 * 32];
    __shared__ unsigned short Bs[128 * 32];
    int t = threadIdx.x;
    int w = t >> 6, l = t & 63;
    int wm = (w >> 1) * 64, wn = (w & 1) * 64;
    int rb = blockIdx.x * 128, cb = blockIdx.y * 128;

    f32x4 acc[4][4] = {};

    for (int kt = 0; kt < PW; kt += 32) {
        #pragma unroll
        for (int q = 0; q < 2; ++q) {
            int e = q * 256 + t;
            int row = e >> 2, seg = e & 3;
            GLL(packA + (size_t)(rb + row) * PW + kt + seg * 8, &As[e * 8]);
            GLL(packB + (size_t)(cb + row) * PW + kt + seg * 8, &Bs[e * 8]);
        }
        __syncthreads();
        s16x8 af[4], bfr[4];
        #pragma unroll
        for (int mf = 0; mf < 4; ++mf)
            af[mf] = *(const s16x8*)&As[(wm + mf * 16 + (l & 15)) * 32 + (l >> 4) * 8];
        #pragma unroll
        for (int nf = 0; nf < 4; ++nf)
            bfr[nf] = *(const s16x8*)&Bs[(wn + nf * 16 + (l & 15)) * 32 + (l >> 4) * 8];
        #pragma unroll
        for (int mf = 0; mf < 4; ++mf)
            #pragma unroll
            for (int nf = 0; nf < 4; ++nf)
                acc[mf][nf] = __builtin_amdgcn_mfma_f32_16x16x32_bf16(af[mf], bfr[nf], acc[mf][nf], 0, 0, 0);
        __syncthreads();
    }

    // epilogue: + gaussian + tanh bias.  C/D layout: col=l&15, row=(l>>4)*4+v
    float fj[4], sqj[4], pj0[4], pj1[4];
    int cc[4];
    #pragma unroll
    for (int nf = 0; nf < 4; ++nf) {
        int c = cb + wn + nf * 16 + (l & 15);
        cc[nf] = c;
        fj[nf] = fbuf[c]; sqj[nf] = sqbuf[c];
        pj0[nf] = pos[2*c]; pj1[nf] = pos[2*c+1];
    }
    #pragma unroll
    for (int mf = 0; mf < 4; ++mf) {
        #pragma unroll
        for (int v = 0; v < 4; ++v) {
            int r = rb + wm + mf * 16 + ((l >> 4) << 2) + v;
            float fi = fbuf[r], sqi = sqbuf[r];
            float pi0 = pos[2*r], pi1 = pos[2*r+1];
            #pragma unroll
            for (int nf = 0; nf < 4; ++nf) {
                float d2 = __builtin_fmaxf(sqi + sqj[nf] - 2.f * (pi0 * pj0[nf] + pi1 * pj1[nf]), 0.f);
                S[(size_t)r * Nn + cc[nf]] = acc[mf][nf][v] + __expf(-0.5f * d2) + tanh_fast(fi - fj[nf]);
            }
        }
    }
}

// ---------------------------------------------------------------- k_rowstats
__global__ __launch_bounds__(256) void k_rowstats(const float* __restrict__ S,
                                                  float* __restrict__ mbuf,
                                                  float* __restrict__ lbuf) {
    int r = blockIdx.x, t = threadIdx.x;
    const float4* row = (const float4*)(S + (size_t)r * Nn);
    float4 v0 = row[t], v1 = row[t + 256], v2 = row[t + 512], v3 = row[t + 768];
    __shared__ float red[256];
    float mx = __builtin_fmaxf(
        __builtin_fmaxf(__builtin_fmaxf(__builtin_fmaxf(v0.x, v0.y), __builtin_fmaxf(v0.z, v0.w)),
                        __builtin_fmaxf(__builtin_fmaxf(v1.x, v1.y), __builtin_fmaxf(v1.z, v1.w))),
        __builtin_fmaxf(__builtin_fmaxf(__builtin_fmaxf(v2.x, v2.y), __builtin_fmaxf(v2.z, v2.w)),
                        __builtin_fmaxf(__builtin_fmaxf(v3.x, v3.y), __builtin_fmaxf(v3.z, v3.w))));
    red[t] = mx;
    __syncthreads();
    for (int s = 128; s > 0; s >>= 1) {
        if (t < s) red[t] = __builtin_fmaxf(red[t], red[t + s]);
        __syncthreads();
    }
    mx = red[0];
    __syncthreads();
    float sum = __expf(v0.x - mx) + __expf(v0.y - mx) + __expf(v0.z - mx) + __expf(v0.w - mx)
              + __expf(v1.x - mx) + __expf(v1.y - mx) + __expf(v1.z - mx) + __expf(v1.w - mx)
              + __expf(v2.x - mx) + __expf(v2.y - mx) + __expf(v2.z - mx) + __expf(v2.w - mx)
              + __expf(v3.x - mx) + __expf(v3.y - mx) + __expf(v3.z - mx) + __expf(v3.w - mx);
    red[t] = sum;
    __syncthreads();
    for (int s = 128; s > 0; s >>= 1) {
        if (t < s) red[t] += red[t + s];
        __syncthreads();
    }
    if (t == 0) { mbuf[r] = mx; lbuf[r] = 1.f / red[0]; }
}

// ---------------------------------------------------------------- k_out
// Fused: read raw logits once, normalize -> write final weights in place,
// cvt bf16 -> LDS, MFMA vs Vt into fp32 k-split partials.
// grid (Nn/64 row-blocks, 4 k-chunks); 4 waves; per wave 64 rows x 64 cols = 4x4 frags.
__global__ __launch_bounds__(256) void k_out(float* __restrict__ S,
                                             const unsigned short* __restrict__ Vt,
                                             const float* __restrict__ mbuf,
                                             const float* __restrict__ lbuf,
                                             float* __restrict__ Opart) {
    __shared__ unsigned short As[64 * 32];
    __shared__ unsigned short Bs[256 * 32];
    __shared__ float sm[64], sl[64];
    int t = threadIdx.x;
    int w = t >> 6, l = t & 63;
    int rb = blockIdx.x * 64;
    int k0 = blockIdx.y * 1024;                   // k-chunk
    if (t < 64) { sm[t] = mbuf[rb + t]; sl[t] = lbuf[rb + t]; }
    __syncthreads();

    f32x4 acc[4][4] = {};

    for (int kt = 0; kt < 1024; kt += 32) {
        // B: all 256 Vt rows x 32 k, direct-to-LDS.  16 KB -> 1024 GLL issues.
        #pragma unroll
        for (int q = 0; q < 4; ++q) {
            int e = q * 256 + t;                  // [0,1024)
            int row = e >> 2, seg = e & 3;
            GLL(Vt + (size_t)row * Nn + k0 + kt + seg * 8, &Bs[e * 8]);
        }
        // A: raw logits -> normalize -> write weights -> bf16 LDS
        #pragma unroll
        for (int q = 0; q < 2; ++q) {
            int e = q * 256 + t;                  // [0,512)
            int row = e >> 3, seg = e & 7;
            size_t off = (size_t)(rb + row) * Nn + k0 + kt + seg * 4;
            float4 x = *(const float4*)(S + off);
            float m = sm[row], lv = sl[row];
            x.x = __expf(x.x - m) * lv;
            x.y = __expf(x.y - m) * lv;
            x.z = __expf(x.z - m) * lv;
            x.w = __expf(x.w - m) * lv;
            *(float4*)(S + off) = x;
            u16x4v b;
            b[0] = f2bf(x.x); b[1] = f2bf(x.y); b[2] = f2bf(x.z); b[3] = f2bf(x.w);
            *(u16x4v*)&As[row * 32 + seg * 4] = b;
        }
        __syncthreads();
        s16x8 a[4];
        #pragma unroll
        for (int mf = 0; mf < 4; ++mf)
            a[mf] = *(const s16x8*)&As[(mf * 16 + (l & 15)) * 32 + (l >> 4) * 8];
        #pragma unroll
        for (int nf = 0; nf < 4; ++nf) {
            s16x8 bb = *(const s16x8*)&Bs[(w * 64 + nf * 16 + (l & 15)) * 32 + (l >> 4) * 8];
            #pragma unroll
            for (int mf = 0; mf < 4; ++mf)
                acc[mf][nf] = __builtin_amdgcn_mfma_f32_16x16x32_bf16(a[mf], bb, acc[mf][nf], 0, 0, 0);
        }
        __syncthreads();
    }
    float* dst = Opart + (size_t)blockIdx.y * Nn * Hd;
    #pragma unroll
    for (int mf = 0; mf < 4; ++mf)
        #pragma unroll
        for (int v = 0; v < 4; ++v) {
            int r = rb + mf * 16 + ((l >> 4) << 2) + v;
            #pragma unroll
            for (int nf = 0; nf < 4; ++nf) {
                int c = w * 64 + nf * 16 + (l & 15);
                dst[(size_t)r * Hd + c] = acc[mf][nf][v];
            }
        }
}

// ---------------------------------------------------------------- k_reduce
__global__ __launch_bounds__(256) void k_reduce(const float* __restrict__ P,
                                                float* __restrict__ O) {
    int id = blockIdx.x * 256 + threadIdx.x;      // 262144 float4s
    size_t off = (size_t)id * 4;
    const size_t C = (size_t)Nn * Hd;
    float4 a = *(const float4*)(P + off);
    float4 b = *(const float4*)(P + C + off);
    float4 c = *(const float4*)(P + 2 * C + off);
    float4 d = *(const float4*)(P + 3 * C + off);
    float4 o;
    o.x = a.x + b.x + c.x + d.x;
    o.y = a.y + b.y + c.y + d.y;
    o.z = a.z + b.z + c.z + d.z;
    o.w = a.w + b.w + c.w + d.w;
    *(float4*)(O + off) = o;
}

// ---------------------------------------------------------------- launch
extern "C" void kernel_launch(void* const* d_in, const int* in_sizes, int n_in,
                              void* d_out, int out_size, void* d_ws, size_t ws_size,
                              hipStream_t stream) {
    const float* gene = (const float*)d_in[0];
    const float* pos  = (const float*)d_in[1];
    const float* Wq = (const float*)d_in[2];  const float* bq = (const float*)d_in[3];
    const float* Wk = (const float*)d_in[4];  const float* bk = (const float*)d_in[5];
    const float* Wv = (const float*)d_in[6];  const float* bv = (const float*)d_in[7];
    const float* Ws = (const float*)d_in[8];  const float* bs = (const float*)d_in[9];
    const float* W1 = (const float*)d_in[10]; const float* b1 = (const float*)d_in[11];
    const float* W2 = (const float*)d_in[12]; const float* b2 = (const float*)d_in[13];
    const float* Wf = (const float*)d_in[14]; const float* bf = (const float*)d_in[15];

    char* w8 = (char*)d_ws;
    // layout (bytes): Vt [0,2M) | smalls [2M,2M+80K) | packA/packB [2.125M,14.1M)
    // Opart (16MB) aliases packA/packB (dead after k_logits) -> peak ~18.1MB
    unsigned short* Vt    = (unsigned short*)w8;                      // [256][4096]
    float*  fbuf  = (float*)(w8 + 2097152);
    float*  sqbuf = fbuf + Nn;
    float*  rinvb = sqbuf + Nn;
    float*  mbuf  = rinvb + Nn;
    float*  lbuf  = mbuf + Nn;
    unsigned short* packA = (unsigned short*)(w8 + 2228224);          // [4096][768]
    unsigned short* packB = (unsigned short*)(w8 + 8519680);          // [4096][768]
    float*  Opart = (float*)(w8 + 2228224);                           // [4][4096][256]

    float* S = (float*)d_out;                      // [N][N] attention weights
    float* O = S + (size_t)Nn * Nn;                // [N][256]

    k_norm<<<Nn, 64, 0, stream>>>(gene, pos, rinvb, sqbuf);
    k_mlp<<<Nn / 16, 256, 0, stream>>>(pos, Ws, bs, W1, b1, W2, b2, Wf, bf, fbuf);
    k_qkv<<<dim3(Nn / 128, 6), 256, 0, stream>>>(gene, Wq, bq, Wk, bk, Wv, bv,
                                                 packA, packB, Vt);
    k_pack<<<(Nn * (Gd / 4)) / 256, 256, 0, stream>>>(gene, rinvb, packA, packB);
    k_logits<<<dim3(Nn / 128, Nn / 128), 256, 0, stream>>>(packA, packB, pos,
                                                           fbuf, sqbuf, S);
    k_rowstats<<<Nn, 256, 0, stream>>>(S, mbuf, lbuf);
    k_out<<<dim3(Nn / 64, 4), 256, 0, stream>>>(S, Vt, mbuf, lbuf, Opart);
    k_reduce<<<(Nn * Hd / 4) / 256, 256, 0, stream>>>(Opart, O);
}

// Round 6
// 282.934 us; speedup vs baseline: 3.0170x; 1.2170x over previous
//
#include <hip/hip_runtime.h>

#define Nn 4096
#define Gd 512
#define Hd 256
#define PW 768   // packed operand width: 256 (Q or K) + 512 (normalized gene)

typedef float f32x4 __attribute__((ext_vector_type(4)));
typedef short s16x8 __attribute__((ext_vector_type(8)));
typedef _Float16 f16x8 __attribute__((ext_vector_type(8)));
typedef unsigned short u16x4v __attribute__((ext_vector_type(4)));
typedef unsigned short u16x8v __attribute__((ext_vector_type(8)));

// async global->LDS, 16B per lane; LDS dest must be wave-uniform base + lane*16.
#define GLL(gp, lp) __builtin_amdgcn_global_load_lds((const __attribute__((address_space(1))) void*)(gp), (__attribute__((address_space(3))) void*)(lp), 16, 0, 0)

// fp32 -> bf16 bits, round-to-nearest-even (integer path; no __bf16 types)
__device__ inline unsigned short f2bf(float x) {
    unsigned u = __builtin_bit_cast(unsigned, x);
    return (unsigned short)((u + 0x7FFFu + ((u >> 16) & 1u)) >> 16);
}
// fp32 -> fp16 bits
__device__ inline unsigned short f2h(float x) {
    return __builtin_bit_cast(unsigned short, (_Float16)x);
}

__device__ inline float tanh_fast(float x) {
    x = __builtin_fminf(__builtin_fmaxf(x, -15.f), 15.f);
    float e2 = __expf(2.f * x);
    return (e2 - 1.f) / (e2 + 1.f);
}

// ---------------------------------------------------------------- k_norm
__global__ __launch_bounds__(64) void k_norm(const float* __restrict__ gene,
                                             const float* __restrict__ pos,
                                             float* __restrict__ rinvb,
                                             float* __restrict__ sqbuf) {
    int i = blockIdx.x, t = threadIdx.x;
    const float4* gr = (const float4*)(gene + (size_t)i * Gd);
    float4 a = gr[t], b = gr[t + 64];
    float ss = a.x*a.x + a.y*a.y + a.z*a.z + a.w*a.w
             + b.x*b.x + b.y*b.y + b.z*b.z + b.w*b.w;
    #pragma unroll
    for (int m = 1; m < 64; m <<= 1) ss += __shfl_xor(ss, m, 64);
    if (t == 0) {
        rinvb[i] = 1.f / __builtin_fmaxf(__builtin_sqrtf(ss), 1e-12f);
        float p0 = pos[2*i], p1 = pos[2*i+1];
        sqbuf[i] = p0*p0 + p1*p1;
    }
}

// ---------------------------------------------------------------- k_mlp
__global__ __launch_bounds__(256) void k_mlp(const float* __restrict__ pos,
                                             const float* __restrict__ Ws, const float* __restrict__ bs,
                                             const float* __restrict__ W1, const float* __restrict__ b1,
                                             const float* __restrict__ W2, const float* __restrict__ b2,
                                             const float* __restrict__ Wf, const float* __restrict__ bf,
                                             float* __restrict__ fbuf) {
    __shared__ float s_a[16][Hd];
    __shared__ float s_h[16][Hd];
    __shared__ float sp[32];
    __shared__ float red[256];
    int t = threadIdx.x;
    int i0 = blockIdx.x * 16;
    if (t < 32) sp[t] = pos[i0 * 2 + t];
    __syncthreads();
    float ws0 = Ws[t], ws1 = Ws[Hd + t], bsv = bs[t];
    #pragma unroll
    for (int n = 0; n < 16; ++n)
        s_a[n][t] = sp[2*n] * ws0 + sp[2*n+1] * ws1 + bsv;
    __syncthreads();
    float accs[16];
    #pragma unroll
    for (int n = 0; n < 16; ++n) accs[n] = 0.f;
    for (int k = 0; k < Hd; ++k) {
        float w = W1[k * Hd + t];
        #pragma unroll
        for (int n = 0; n < 16; ++n) accs[n] += s_a[n][k] * w;
    }
    float b1v = b1[t];
    #pragma unroll
    for (int n = 0; n < 16; ++n) s_h[n][t] = tanh_fast(accs[n] + b1v);
    __syncthreads();
    #pragma unroll
    for (int n = 0; n < 16; ++n) accs[n] = 0.f;
    for (int k = 0; k < Hd; ++k) {
        float w = W2[k * Hd + t];
        #pragma unroll
        for (int n = 0; n < 16; ++n) accs[n] += s_h[n][k] * w;
    }
    float b2v = b2[t];
    __syncthreads();
    #pragma unroll
    for (int n = 0; n < 16; ++n) s_a[n][t] = __builtin_fmaxf(accs[n] + b2v, 0.f);
    __syncthreads();
    float wf = Wf[t];
    for (int n = 0; n < 16; ++n) {
        red[t] = s_a[n][t] * wf;
        __syncthreads();
        for (int s = 128; s > 0; s >>= 1) {
            if (t < s) red[t] += red[t + s];
            __syncthreads();
        }
        if (t == 0) fbuf[i0 + n] = red[0] + bf[0];
        __syncthreads();
    }
}

// ---------------------------------------------------------------- k_pack
// normalized gene rows (bf16) into cols [256,768) of packA/packB, and raw
// fp16 gene rows into geneh (MFMA A-operand for k_qkv_mfma).
__global__ __launch_bounds__(256) void k_pack(const float* __restrict__ gene,
                                              const float* __restrict__ rinvb,
                                              unsigned short* __restrict__ packA,
                                              unsigned short* __restrict__ packB,
                                              unsigned short* __restrict__ geneh) {
    int id = blockIdx.x * 256 + threadIdx.x;      // 4096*128 float4s
    int row = id >> 7;
    int c4 = (id & 127) << 2;
    float ri = rinvb[row];
    float4 v = *(const float4*)(gene + (size_t)row * Gd + c4);
    u16x4v h;
    h[0] = f2h(v.x); h[1] = f2h(v.y); h[2] = f2h(v.z); h[3] = f2h(v.w);
    *(u16x4v*)(geneh + (size_t)row * Gd + c4) = h;
    u16x4v b;
    b[0] = f2bf(v.x * ri); b[1] = f2bf(v.y * ri);
    b[2] = f2bf(v.z * ri); b[3] = f2bf(v.w * ri);
    *(u16x4v*)(packA + (size_t)row * PW + Hd + c4) = b;
    *(u16x4v*)(packB + (size_t)row * PW + Hd + c4) = b;
}

// ---------------------------------------------------------------- k_wt
// Wt[768][512] fp16: rows 0-255 = Wq^T, 256-511 = Wk^T, 512-767 = Wv^T.
// 64x64 LDS-tiled transpose, grid (512/64, 768/64).
__global__ __launch_bounds__(256) void k_wt(const float* __restrict__ Wq,
                                            const float* __restrict__ Wk,
                                            const float* __restrict__ Wv,
                                            unsigned short* __restrict__ Wt) {
    __shared__ float tile[64][65];
    int t = threadIdx.x;
    int kb = blockIdx.x * 64;                 // k (input-row) base
    int by = blockIdx.y;
    int mid = by >> 2;                        // 0=Q 1=K 2=V
    int cb2 = (by & 3) * 64;                  // col base within the W matrix
    const float* W = (mid == 0) ? Wq : (mid == 1) ? Wk : Wv;
    #pragma unroll
    for (int q = 0; q < 16; ++q) {
        int idx = q * 256 + t;
        int row = idx >> 6, col = idx & 63;
        tile[row][col] = W[(size_t)(kb + row) * Hd + cb2 + col];
    }
    __syncthreads();
    int crow = by * 64;                       // output (Wt) row base
    #pragma unroll
    for (int q = 0; q < 16; ++q) {
        int idx = q * 256 + t;
        int c = idx >> 6, k = idx & 63;
        Wt[(size_t)(crow + c) * Gd + kb + k] = f2h(tile[k][c]);
    }
}

// ---------------------------------------------------------------- k_qkv_mfma
// C[4096][768] = geneh @ Wt^T  (fp16 MFMA, fp32 acc).
// BM=64, BN=128, BK=32; grid (64, 6); 4 waves 2x2 (32 rows x 64 cols each).
// by 0,1 -> Q (scale 1/16 -> packA); 2,3 -> K (packB); 4,5 -> V (Vt transposed).
__global__ __launch_bounds__(256) void k_qkv_mfma(const unsigned short* __restrict__ geneh,
                                                  const unsigned short* __restrict__ Wt,
                                                  const float* __restrict__ bq,
                                                  const float* __restrict__ bk,
                                                  const float* __restrict__ bv,
                                                  unsigned short* __restrict__ packA,
                                                  unsigned short* __restrict__ packB,
                                                  unsigned short* __restrict__ Vt) {
    __shared__ unsigned short As[64 * 32];
    __shared__ unsigned short Bs[128 * 32];
    int t = threadIdx.x;
    int w = t >> 6, l = t & 63;
    int wm = (w >> 1) * 32, wn = (w & 1) * 64;
    int rb = blockIdx.x * 64;
    int cb = blockIdx.y * 128;                // column in packed [Q|K|V] space
    int mid = blockIdx.y >> 1;                // 0=Q 1=K 2=V (block-uniform)
    const float* bia = (mid == 0) ? bq : (mid == 1) ? bk : bv;

    f32x4 acc[2][4] = {};

    for (int kt = 0; kt < Gd; kt += 32) {
        {   // A: 64 rows x 32 k fp16 = 4KB = 256 issues
            int row = t >> 2, seg = t & 3;
            GLL(geneh + (size_t)(rb + row) * Gd + kt + seg * 8, &As[t * 8]);
        }
        #pragma unroll
        for (int q = 0; q < 2; ++q) {         // B: 128 rows x 32 k = 8KB
            int e = q * 256 + t;
            int row = e >> 2, seg = e & 3;
            GLL(Wt + (size_t)(cb + row) * Gd + kt + seg * 8, &Bs[e * 8]);
        }
        __syncthreads();
        f16x8 af[2], bfr[4];
        #pragma unroll
        for (int mf = 0; mf < 2; ++mf)
            af[mf] = *(const f16x8*)&As[(wm + mf * 16 + (l & 15)) * 32 + (l >> 4) * 8];
        #pragma unroll
        for (int nf = 0; nf < 4; ++nf)
            bfr[nf] = *(const f16x8*)&Bs[(wn + nf * 16 + (l & 15)) * 32 + (l >> 4) * 8];
        #pragma unroll
        for (int mf = 0; mf < 2; ++mf)
            #pragma unroll
            for (int nf = 0; nf < 4; ++nf)
                acc[mf][nf] = __builtin_amdgcn_mfma_f32_16x16x32_f16(af[mf], bfr[nf], acc[mf][nf], 0, 0, 0);
        __syncthreads();
    }

    // epilogue.  C/D layout: col = l&15, row = (l>>4)*4 + v
    float scale = (mid == 0) ? 0.0625f : 1.f;
    #pragma unroll
    for (int nf = 0; nf < 4; ++nf) {
        int cg = cb + wn + nf * 16 + (l & 15);           // global packed col
        int cloc = cg - mid * 256;                       // col within Q/K/V
        float bb = bia[cloc];
        #pragma unroll
        for (int mf = 0; mf < 2; ++mf) {
            int r0 = rb + wm + mf * 16 + ((l >> 4) << 2);
            if (mid == 2) {
                u16x4v o;
                #pragma unroll
                for (int v = 0; v < 4; ++v) o[v] = f2bf(acc[mf][nf][v] + bb);
                *(u16x4v*)(Vt + (size_t)cloc * Nn + r0) = o;
            } else {
                unsigned short* dst = (mid == 0) ? packA : packB;
                #pragma unroll
                for (int v = 0; v < 4; ++v)
                    dst[(size_t)(r0 + v) * PW + cloc] = f2bf((acc[mf][nf][v] + bb) * scale);
            }
        }
    }
}

// ---------------------------------------------------------------- k_logits
// S = packA @ packB^T (bf16 MFMA, fp32 acc) + exp(-d2/2) + tanh(fi-fj).
// 128x128 tile, BK=32, 4 waves (2x2), each wave 64x64 = 4x4 frags 16x16x32.
__global__ __launch_bounds__(256) void k_logits(const unsigned short* __restrict__ packA,
                                                const unsigned short* __restrict__ packB,
                                                const float* __restrict__ pos,
                                                const float* __restrict__ fbuf,
                                                const float* __restrict__ sqbuf,
                                                float* __restrict__ S) {
    __shared__ unsigned short As[128 * 32];
    __shared__ unsigned short Bs[128 * 32];
    int t = threadIdx.x;
    int w = t >> 6, l = t & 63;
    int wm = (w >> 1) * 64, wn = (w & 1) * 64;
    int rb = blockIdx.x * 128, cb = blockIdx.y * 128;

    f32x4 acc[4][4] = {};

    for (int kt = 0; kt < PW; kt += 32) {
        #pragma unroll
        for (int q = 0; q < 2; ++q) {
            int e = q * 256 + t;
            int row = e >> 2, seg = e & 3;
            GLL(packA + (size_t)(rb + row) * PW + kt + seg * 8, &As[e * 8]);
            GLL(packB + (size_t)(cb + row) * PW + kt + seg * 8, &Bs[e * 8]);
        }
        __syncthreads();
        s16x8 af[4], bfr[4];
        #pragma unroll
        for (int mf = 0; mf < 4; ++mf)
            af[mf] = *(const s16x8*)&As[(wm + mf * 16 + (l & 15)) * 32 + (l >> 4) * 8];
        #pragma unroll
        for (int nf = 0; nf < 4; ++nf)
            bfr[nf] = *(const s16x8*)&Bs[(wn + nf * 16 + (l & 15)) * 32 + (l >> 4) * 8];
        #pragma unroll
        for (int mf = 0; mf < 4; ++mf)
            #pragma unroll
            for (int nf = 0; nf < 4; ++nf)
                acc[mf][nf] = __builtin_amdgcn_mfma_f32_16x16x32_bf16(af[mf], bfr[nf], acc[mf][nf], 0, 0, 0);
        __syncthreads();
    }

    // epilogue: + gaussian + tanh bias.  C/D layout: col=l&15, row=(l>>4)*4+v
    float fj[4], sqj[4], pj0[4], pj1[4];
    int cc[4];
    #pragma unroll
    for (int nf = 0; nf < 4; ++nf) {
        int c = cb + wn + nf * 16 + (l & 15);
        cc[nf] = c;
        fj[nf] = fbuf[c]; sqj[nf] = sqbuf[c];
        pj0[nf] = pos[2*c]; pj1[nf] = pos[2*c+1];
    }
    #pragma unroll
    for (int mf = 0; mf < 4; ++mf) {
        #pragma unroll
        for (int v = 0; v < 4; ++v) {
            int r = rb + wm + mf * 16 + ((l >> 4) << 2) + v;
            float fi = fbuf[r], sqi = sqbuf[r];
            float pi0 = pos[2*r], pi1 = pos[2*r+1];
            #pragma unroll
            for (int nf = 0; nf < 4; ++nf) {
                float d2 = __builtin_fmaxf(sqi + sqj[nf] - 2.f * (pi0 * pj0[nf] + pi1 * pj1[nf]), 0.f);
                S[(size_t)r * Nn + cc[nf]] = acc[mf][nf][v] + __expf(-0.5f * d2) + tanh_fast(fi - fj[nf]);
            }
        }
    }
}

// ---------------------------------------------------------------- k_rowstats
__global__ __launch_bounds__(256) void k_rowstats(const float* __restrict__ S,
                                                  float* __restrict__ mbuf,
                                                  float* __restrict__ lbuf) {
    int r = blockIdx.x, t = threadIdx.x;
    const float4* row = (const float4*)(S + (size_t)r * Nn);
    float4 v0 = row[t], v1 = row[t + 256], v2 = row[t + 512], v3 = row[t + 768];
    __shared__ float red[256];
    float mx = __builtin_fmaxf(
        __builtin_fmaxf(__builtin_fmaxf(__builtin_fmaxf(v0.x, v0.y), __builtin_fmaxf(v0.z, v0.w)),
                        __builtin_fmaxf(__builtin_fmaxf(v1.x, v1.y), __builtin_fmaxf(v1.z, v1.w))),
        __builtin_fmaxf(__builtin_fmaxf(__builtin_fmaxf(v2.x, v2.y), __builtin_fmaxf(v2.z, v2.w)),
                        __builtin_fmaxf(__builtin_fmaxf(v3.x, v3.y), __builtin_fmaxf(v3.z, v3.w))));
    red[t] = mx;
    __syncthreads();
    for (int s = 128; s > 0; s >>= 1) {
        if (t < s) red[t] = __builtin_fmaxf(red[t], red[t + s]);
        __syncthreads();
    }
    mx = red[0];
    __syncthreads();
    float sum = __expf(v0.x - mx) + __expf(v0.y - mx) + __expf(v0.z - mx) + __expf(v0.w - mx)
              + __expf(v1.x - mx) + __expf(v1.y - mx) + __expf(v1.z - mx) + __expf(v1.w - mx)
              + __expf(v2.x - mx) + __expf(v2.y - mx) + __expf(v2.z - mx) + __expf(v2.w - mx)
              + __expf(v3.x - mx) + __expf(v3.y - mx) + __expf(v3.z - mx) + __expf(v3.w - mx);
    red[t] = sum;
    __syncthreads();
    for (int s = 128; s > 0; s >>= 1) {
        if (t < s) red[t] += red[t + s];
        __syncthreads();
    }
    if (t == 0) { mbuf[r] = mx; lbuf[r] = 1.f / red[0]; }
}

// ---------------------------------------------------------------- k_out
// Fused: read raw logits once, normalize -> write final weights in place,
// cvt bf16 -> LDS, MFMA vs Vt into fp32 k-split partials.
__global__ __launch_bounds__(256) void k_out(float* __restrict__ S,
                                             const unsigned short* __restrict__ Vt,
                                             const float* __restrict__ mbuf,
                                             const float* __restrict__ lbuf,
                                             float* __restrict__ Opart) {
    __shared__ unsigned short As[64 * 32];
    __shared__ unsigned short Bs[256 * 32];
    __shared__ float sm[64], sl[64];
    int t = threadIdx.x;
    int w = t >> 6, l = t & 63;
    int rb = blockIdx.x * 64;
    int k0 = blockIdx.y * 1024;                   // k-chunk
    if (t < 64) { sm[t] = mbuf[rb + t]; sl[t] = lbuf[rb + t]; }
    __syncthreads();

    f32x4 acc[4][4] = {};

    for (int kt = 0; kt < 1024; kt += 32) {
        // B: all 256 Vt rows x 32 k = 16KB -> 1024 GLL issues
        #pragma unroll
        for (int q = 0; q < 4; ++q) {
            int e = q * 256 + t;
            int row = e >> 2, seg = e & 3;
            GLL(Vt + (size_t)row * Nn + k0 + kt + seg * 8, &Bs[e * 8]);
        }
        // A: raw logits -> normalize -> write weights -> bf16 LDS
        #pragma unroll
        for (int q = 0; q < 2; ++q) {
            int e = q * 256 + t;
            int row = e >> 3, seg = e & 7;
            size_t off = (size_t)(rb + row) * Nn + k0 + kt + seg * 4;
            float4 x = *(const float4*)(S + off);
            float m = sm[row], lv = sl[row];
            x.x = __expf(x.x - m) * lv;
            x.y = __expf(x.y - m) * lv;
            x.z = __expf(x.z - m) * lv;
            x.w = __expf(x.w - m) * lv;
            *(float4*)(S + off) = x;
            u16x4v b;
            b[0] = f2bf(x.x); b[1] = f2bf(x.y); b[2] = f2bf(x.z); b[3] = f2bf(x.w);
            *(u16x4v*)&As[row * 32 + seg * 4] = b;
        }
        __syncthreads();
        s16x8 a[4];
        #pragma unroll
        for (int mf = 0; mf < 4; ++mf)
            a[mf] = *(const s16x8*)&As[(mf * 16 + (l & 15)) * 32 + (l >> 4) * 8];
        #pragma unroll
        for (int nf = 0; nf < 4; ++nf) {
            s16x8 bb = *(const s16x8*)&Bs[(w * 64 + nf * 16 + (l & 15)) * 32 + (l >> 4) * 8];
            #pragma unroll
            for (int mf = 0; mf < 4; ++mf)
                acc[mf][nf] = __builtin_amdgcn_mfma_f32_16x16x32_bf16(a[mf], bb, acc[mf][nf], 0, 0, 0);
        }
        __syncthreads();
    }
    float* dst = Opart + (size_t)blockIdx.y * Nn * Hd;
    #pragma unroll
    for (int mf = 0; mf < 4; ++mf)
        #pragma unroll
        for (int v = 0; v < 4; ++v) {
            int r = rb + mf * 16 + ((l >> 4) << 2) + v;
            #pragma unroll
            for (int nf = 0; nf < 4; ++nf) {
                int c = w * 64 + nf * 16 + (l & 15);
                dst[(size_t)r * Hd + c] = acc[mf][nf][v];
            }
        }
}

// ---------------------------------------------------------------- k_reduce
__global__ __launch_bounds__(256) void k_reduce(const float* __restrict__ P,
                                                float* __restrict__ O) {
    int id = blockIdx.x * 256 + threadIdx.x;
    size_t off = (size_t)id * 4;
    const size_t C = (size_t)Nn * Hd;
    float4 a = *(const float4*)(P + off);
    float4 b = *(const float4*)(P + C + off);
    float4 c = *(const float4*)(P + 2 * C + off);
    float4 d = *(const float4*)(P + 3 * C + off);
    float4 o;
    o.x = a.x + b.x + c.x + d.x;
    o.y = a.y + b.y + c.y + d.y;
    o.z = a.z + b.z + c.z + d.z;
    o.w = a.w + b.w + c.w + d.w;
    *(float4*)(O + off) = o;
}

// ---------------------------------------------------------------- launch
extern "C" void kernel_launch(void* const* d_in, const int* in_sizes, int n_in,
                              void* d_out, int out_size, void* d_ws, size_t ws_size,
                              hipStream_t stream) {
    const float* gene = (const float*)d_in[0];
    const float* pos  = (const float*)d_in[1];
    const float* Wq = (const float*)d_in[2];  const float* bq = (const float*)d_in[3];
    const float* Wk = (const float*)d_in[4];  const float* bk = (const float*)d_in[5];
    const float* Wv = (const float*)d_in[6];  const float* bv = (const float*)d_in[7];
    const float* Ws = (const float*)d_in[8];  const float* bs = (const float*)d_in[9];
    const float* W1 = (const float*)d_in[10]; const float* b1 = (const float*)d_in[11];
    const float* W2 = (const float*)d_in[12]; const float* b2 = (const float*)d_in[13];
    const float* Wf = (const float*)d_in[14]; const float* bf = (const float*)d_in[15];

    char* w8 = (char*)d_ws;
    // bytes: Vt [0,2M) | smalls [2M,2.125M) | packA [2.125M,8.4M) | packB
    // [8.4M,14.8M) | geneh [14.8M,19M) | Wt [19M,19.8M).
    // Opart (16.77MB) aliases packA+packB+geneh exactly (all dead by k_out).
    unsigned short* Vt    = (unsigned short*)w8;                      // [256][4096]
    float*  fbuf  = (float*)(w8 + 2097152);
    float*  sqbuf = fbuf + Nn;
    float*  rinvb = sqbuf + Nn;
    float*  mbuf  = rinvb + Nn;
    float*  lbuf  = mbuf + Nn;
    unsigned short* packA = (unsigned short*)(w8 + 2228224);          // [4096][768]
    unsigned short* packB = (unsigned short*)(w8 + 8519680);          // [4096][768]
    unsigned short* geneh = (unsigned short*)(w8 + 14811136);         // [4096][512]
    unsigned short* Wt    = (unsigned short*)(w8 + 19005440);         // [768][512]
    float*  Opart = (float*)(w8 + 2228224);                           // [4][4096][256]

    float* S = (float*)d_out;                      // [N][N] attention weights
    float* O = S + (size_t)Nn * Nn;                // [N][256]

    k_norm<<<Nn, 64, 0, stream>>>(gene, pos, rinvb, sqbuf);
    k_mlp<<<Nn / 16, 256, 0, stream>>>(pos, Ws, bs, W1, b1, W2, b2, Wf, bf, fbuf);
    k_pack<<<(Nn * (Gd / 4)) / 256, 256, 0, stream>>>(gene, rinvb, packA, packB, geneh);
    k_wt<<<dim3(Gd / 64, PW / 64), 256, 0, stream>>>(Wq, Wk, Wv, Wt);
    k_qkv_mfma<<<dim3(Nn / 64, 6), 256, 0, stream>>>(geneh, Wt, bq, bk, bv,
                                                     packA, packB, Vt);
    k_logits<<<dim3(Nn / 128, Nn / 128), 256, 0, stream>>>(packA, packB, pos,
                                                           fbuf, sqbuf, S);
    k_rowstats<<<Nn, 256, 0, stream>>>(S, mbuf, lbuf);
    k_out<<<dim3(Nn / 64, 4), 256, 0, stream>>>(S, Vt, mbuf, lbuf, Opart);
    k_reduce<<<(Nn * Hd / 4) / 256, 256, 0, stream>>>(Opart, O);
}

// Round 9
// 247.022 us; speedup vs baseline: 3.4557x; 1.1454x over previous
//
#include <hip/hip_runtime.h>

#define Nn 4096
#define Gd 512
#define Hd 256
#define PW 768   // packed operand width: 256 (Q or K) + 512 (normalized gene)

typedef float f32x4 __attribute__((ext_vector_type(4)));
typedef short s16x8 __attribute__((ext_vector_type(8)));
typedef _Float16 f16x8 __attribute__((ext_vector_type(8)));
typedef unsigned short u16x4v __attribute__((ext_vector_type(4)));
typedef unsigned short u16x8v __attribute__((ext_vector_type(8)));

// async global->LDS, 16B per lane; LDS dest must be wave-uniform base + lane*16.
#define GLL(gp, lp) __builtin_amdgcn_global_load_lds((const __attribute__((address_space(1))) void*)(gp), (__attribute__((address_space(3))) void*)(lp), 16, 0, 0)

// fp32 -> bf16 bits, round-to-nearest-even (integer path; no __bf16 types)
__device__ inline unsigned short f2bf(float x) {
    unsigned u = __builtin_bit_cast(unsigned, x);
    return (unsigned short)((u + 0x7FFFu + ((u >> 16) & 1u)) >> 16);
}
// fp32 -> fp16 bits
__device__ inline unsigned short f2h(float x) {
    return __builtin_bit_cast(unsigned short, (_Float16)x);
}

__device__ inline float tanh_fast(float x) {
    x = __builtin_fminf(__builtin_fmaxf(x, -15.f), 15.f);
    float e2 = __expf(2.f * x);
    return (e2 - 1.f) / (e2 + 1.f);
}

// ---------------------------------------------------------------- k_norm
__global__ __launch_bounds__(64) void k_norm(const float* __restrict__ gene,
                                             const float* __restrict__ pos,
                                             float* __restrict__ rinvb,
                                             float* __restrict__ sqbuf) {
    int i = blockIdx.x, t = threadIdx.x;
    const float4* gr = (const float4*)(gene + (size_t)i * Gd);
    float4 a = gr[t], b = gr[t + 64];
    float ss = a.x*a.x + a.y*a.y + a.z*a.z + a.w*a.w
             + b.x*b.x + b.y*b.y + b.z*b.z + b.w*b.w;
    #pragma unroll
    for (int m = 1; m < 64; m <<= 1) ss += __shfl_xor(ss, m, 64);
    if (t == 0) {
        rinvb[i] = 1.f / __builtin_fmaxf(__builtin_sqrtf(ss), 1e-12f);
        float p0 = pos[2*i], p1 = pos[2*i+1];
        sqbuf[i] = p0*p0 + p1*p1;
    }
}

// ---------------------------------------------------------------- k_wt
// Wt[768][512] fp16: rows 0-255 = Wq^T, 256-511 = Wk^T, 512-767 = Wv^T.
__global__ __launch_bounds__(256) void k_wt(const float* __restrict__ Wq,
                                            const float* __restrict__ Wk,
                                            const float* __restrict__ Wv,
                                            unsigned short* __restrict__ Wt) {
    __shared__ float tile[64][65];
    int t = threadIdx.x;
    int kb = blockIdx.x * 64;
    int by = blockIdx.y;
    int mid = by >> 2;
    int cb2 = (by & 3) * 64;
    const float* W = (mid == 0) ? Wq : (mid == 1) ? Wk : Wv;
    #pragma unroll
    for (int q = 0; q < 16; ++q) {
        int idx = q * 256 + t;
        int row = idx >> 6, col = idx & 63;
        tile[row][col] = W[(size_t)(kb + row) * Hd + cb2 + col];
    }
    __syncthreads();
    int crow = by * 64;
    #pragma unroll
    for (int q = 0; q < 16; ++q) {
        int idx = q * 256 + t;
        int c = idx >> 6, k = idx & 63;
        Wt[(size_t)(crow + c) * Gd + kb + k] = f2h(tile[k][c]);
    }
}

// ---------------------------------------------------------------- k_wt2
// W1t/W2t [256][256] fp16 transposes of W1/W2 (for MLP MFMA B operand).
__global__ __launch_bounds__(256) void k_wt2(const float* __restrict__ W1,
                                             const float* __restrict__ W2,
                                             unsigned short* __restrict__ W1t,
                                             unsigned short* __restrict__ W2t) {
    __shared__ float tile[64][65];
    int t = threadIdx.x;
    int kb = blockIdx.x * 64;                 // input-row (k) base
    int by = blockIdx.y;
    int mid = by >> 2;                        // 0=W1 1=W2
    int cb2 = (by & 3) * 64;                  // input-col base
    const float* W = (mid == 0) ? W1 : W2;
    unsigned short* Wo = (mid == 0) ? W1t : W2t;
    #pragma unroll
    for (int q = 0; q < 16; ++q) {
        int idx = q * 256 + t;
        int row = idx >> 6, col = idx & 63;
        tile[row][col] = W[(size_t)(kb + row) * Hd + cb2 + col];
    }
    __syncthreads();
    #pragma unroll
    for (int q = 0; q < 16; ++q) {
        int idx = q * 256 + t;
        int c = idx >> 6, k = idx & 63;
        Wo[(size_t)(cb2 + c) * Hd + kb + k] = f2h(tile[k][c]);
    }
}

// ---------------------------------------------------------------- k_mlp_mfma
// fbuf[i] = Wf . relu(W2t_mm(tanh(W1t_mm(si)))) + bf, si = pos@Ws+bs.
// grid 256 x (16 rows); 4 waves, wave w owns output cols [w*64, w*64+64).
__global__ __launch_bounds__(256) void k_mlp_mfma(const float* __restrict__ pos,
                                                  const float* __restrict__ Ws, const float* __restrict__ bs,
                                                  const unsigned short* __restrict__ W1t, const float* __restrict__ b1,
                                                  const unsigned short* __restrict__ W2t, const float* __restrict__ b2,
                                                  const float* __restrict__ Wf, const float* __restrict__ bf,
                                                  float* __restrict__ fbuf) {
    __shared__ unsigned short A_lds[16 * 256];   // si (fp16)
    __shared__ unsigned short H_lds[16 * 256];   // tanh hidden (fp16)
    __shared__ unsigned short Bs_[256 * 32];     // W tile [n][k]
    __shared__ float E_lds[16][256];             // relu out (fp32)
    __shared__ float sp_[32];
    int t = threadIdx.x;
    int w = t >> 6, l = t & 63;
    int rb = blockIdx.x * 16;
    if (t < 32) sp_[t] = pos[rb * 2 + t];
    __syncthreads();
    // si[r][c] = p0*Ws[0][c] + p1*Ws[1][c] + bs[c]
    #pragma unroll
    for (int q = 0; q < 16; ++q) {
        float v = sp_[2*q] * Ws[t] + sp_[2*q+1] * Ws[Hd + t] + bs[t];
        A_lds[q * 256 + t] = f2h(v);
    }
    __syncthreads();

    // GEMM1: z1 = si @ W1   (A=si [16][256], B=W1t [n][k])
    f32x4 acc[4] = {};
    for (int kt = 0; kt < Hd; kt += 32) {
        #pragma unroll
        for (int q = 0; q < 4; ++q) {
            int e = q * 256 + t;
            int row = e >> 2, seg = e & 3;
            GLL(W1t + (size_t)row * Hd + kt + seg * 8, &Bs_[e * 8]);
        }
        __syncthreads();
        f16x8 af = *(const f16x8*)&A_lds[(l & 15) * 256 + kt + (l >> 4) * 8];
        #pragma unroll
        for (int nf = 0; nf < 4; ++nf) {
            f16x8 bb = *(const f16x8*)&Bs_[(w * 64 + nf * 16 + (l & 15)) * 32 + (l >> 4) * 8];
            acc[nf] = __builtin_amdgcn_mfma_f32_16x16x32_f16(af, bb, acc[nf], 0, 0, 0);
        }
        __syncthreads();
    }
    #pragma unroll
    for (int nf = 0; nf < 4; ++nf) {
        int c = w * 64 + nf * 16 + (l & 15);
        float bb = b1[c];
        #pragma unroll
        for (int v = 0; v < 4; ++v) {
            int r = ((l >> 4) << 2) + v;
            H_lds[r * 256 + c] = f2h(tanh_fast(acc[nf][v] + bb));
        }
    }
    __syncthreads();

    // GEMM2: z2 = h @ W2
    f32x4 acc2[4] = {};
    for (int kt = 0; kt < Hd; kt += 32) {
        #pragma unroll
        for (int q = 0; q < 4; ++q) {
            int e = q * 256 + t;
            int row = e >> 2, seg = e & 3;
            GLL(W2t + (size_t)row * Hd + kt + seg * 8, &Bs_[e * 8]);
        }
        __syncthreads();
        f16x8 af = *(const f16x8*)&H_lds[(l & 15) * 256 + kt + (l >> 4) * 8];
        #pragma unroll
        for (int nf = 0; nf < 4; ++nf) {
            f16x8 bb = *(const f16x8*)&Bs_[(w * 64 + nf * 16 + (l & 15)) * 32 + (l >> 4) * 8];
            acc2[nf] = __builtin_amdgcn_mfma_f32_16x16x32_f16(af, bb, acc2[nf], 0, 0, 0);
        }
        __syncthreads();
    }
    #pragma unroll
    for (int nf = 0; nf < 4; ++nf) {
        int c = w * 64 + nf * 16 + (l & 15);
        float bb = b2[c];
        #pragma unroll
        for (int v = 0; v < 4; ++v)
            E_lds[((l >> 4) << 2) + v][c] = __builtin_fmaxf(acc2[nf][v] + bb, 0.f);
    }
    __syncthreads();

    // f[r] = E[r] . Wf + bf ; wave w reduces rows w*4 .. w*4+3
    f32x4 wf4 = *(const f32x4*)&Wf[l * 4];
    #pragma unroll
    for (int rr = 0; rr < 4; ++rr) {
        int r = w * 4 + rr;
        f32x4 ev = *(const f32x4*)&E_lds[r][l * 4];
        float s = ev[0]*wf4[0] + ev[1]*wf4[1] + ev[2]*wf4[2] + ev[3]*wf4[3];
        #pragma unroll
        for (int m = 1; m < 64; m <<= 1) s += __shfl_xor(s, m, 64);
        if (l == 0) fbuf[rb + r] = s + bf[0];
    }
}

// ---------------------------------------------------------------- k_pack
__global__ __launch_bounds__(256) void k_pack(const float* __restrict__ gene,
                                              const float* __restrict__ rinvb,
                                              unsigned short* __restrict__ packA,
                                              unsigned short* __restrict__ packB,
                                              unsigned short* __restrict__ geneh) {
    int id = blockIdx.x * 256 + threadIdx.x;      // 4096*128 float4s
    int row = id >> 7;
    int c4 = (id & 127) << 2;
    float ri = rinvb[row];
    float4 v = *(const float4*)(gene + (size_t)row * Gd + c4);
    u16x4v h;
    h[0] = f2h(v.x); h[1] = f2h(v.y); h[2] = f2h(v.z); h[3] = f2h(v.w);
    *(u16x4v*)(geneh + (size_t)row * Gd + c4) = h;
    u16x4v b;
    b[0] = f2bf(v.x * ri); b[1] = f2bf(v.y * ri);
    b[2] = f2bf(v.z * ri); b[3] = f2bf(v.w * ri);
    *(u16x4v*)(packA + (size_t)row * PW + Hd + c4) = b;
    *(u16x4v*)(packB + (size_t)row * PW + Hd + c4) = b;
}

// ---------------------------------------------------------------- k_qkv_mfma
// C[4096][768] = geneh @ Wt^T  (fp16 MFMA, fp32 acc).
__global__ __launch_bounds__(256) void k_qkv_mfma(const unsigned short* __restrict__ geneh,
                                                  const unsigned short* __restrict__ Wt,
                                                  const float* __restrict__ bq,
                                                  const float* __restrict__ bk,
                                                  const float* __restrict__ bv,
                                                  unsigned short* __restrict__ packA,
                                                  unsigned short* __restrict__ packB,
                                                  unsigned short* __restrict__ Vt) {
    __shared__ unsigned short As[64 * 32];
    __shared__ unsigned short Bs[128 * 32];
    int t = threadIdx.x;
    int w = t >> 6, l = t & 63;
    int wm = (w >> 1) * 32, wn = (w & 1) * 64;
    int rb = blockIdx.x * 64;
    int cb = blockIdx.y * 128;
    int mid = blockIdx.y >> 1;
    const float* bia = (mid == 0) ? bq : (mid == 1) ? bk : bv;

    f32x4 acc[2][4] = {};

    for (int kt = 0; kt < Gd; kt += 32) {
        {
            int row = t >> 2, seg = t & 3;
            GLL(geneh + (size_t)(rb + row) * Gd + kt + seg * 8, &As[t * 8]);
        }
        #pragma unroll
        for (int q = 0; q < 2; ++q) {
            int e = q * 256 + t;
            int row = e >> 2, seg = e & 3;
            GLL(Wt + (size_t)(cb + row) * Gd + kt + seg * 8, &Bs[e * 8]);
        }
        __syncthreads();
        f16x8 af[2], bfr[4];
        #pragma unroll
        for (int mf = 0; mf < 2; ++mf)
            af[mf] = *(const f16x8*)&As[(wm + mf * 16 + (l & 15)) * 32 + (l >> 4) * 8];
        #pragma unroll
        for (int nf = 0; nf < 4; ++nf)
            bfr[nf] = *(const f16x8*)&Bs[(wn + nf * 16 + (l & 15)) * 32 + (l >> 4) * 8];
        #pragma unroll
        for (int mf = 0; mf < 2; ++mf)
            #pragma unroll
            for (int nf = 0; nf < 4; ++nf)
                acc[mf][nf] = __builtin_amdgcn_mfma_f32_16x16x32_f16(af[mf], bfr[nf], acc[mf][nf], 0, 0, 0);
        __syncthreads();
    }

    float scale = (mid == 0) ? 0.0625f : 1.f;
    #pragma unroll
    for (int nf = 0; nf < 4; ++nf) {
        int cg = cb + wn + nf * 16 + (l & 15);
        int cloc = cg - mid * 256;
        float bb = bia[cloc];
        #pragma unroll
        for (int mf = 0; mf < 2; ++mf) {
            int r0 = rb + wm + mf * 16 + ((l >> 4) << 2);
            if (mid == 2) {
                u16x4v o;
                #pragma unroll
                for (int v = 0; v < 4; ++v) o[v] = f2bf(acc[mf][nf][v] + bb);
                *(u16x4v*)(Vt + (size_t)cloc * Nn + r0) = o;
            } else {
                unsigned short* dst = (mid == 0) ? packA : packB;
                #pragma unroll
                for (int v = 0; v < 4; ++v)
                    dst[(size_t)(r0 + v) * PW + cloc] = f2bf((acc[mf][nf][v] + bb) * scale);
            }
        }
    }
}

// ---------------------------------------------------------------- k_logits
__global__ __launch_bounds__(256) void k_logits(const unsigned short* __restrict__ packA,
                                                const unsigned short* __restrict__ packB,
                                                const float* __restrict__ pos,
                                                const float* __restrict__ fbuf,
                                                const float* __restrict__ sqbuf,
                                                float* __restrict__ S) {
    __shared__ unsigned short As[128 * 32];
    __shared__ unsigned short Bs[128 * 32];
    int t = threadIdx.x;
    int w = t >> 6, l = t & 63;
    int wm = (w >> 1) * 64, wn = (w & 1) * 64;
    int rb = blockIdx.x * 128, cb = blockIdx.y * 128;

    f32x4 acc[4][4] = {};

    for (int kt = 0; kt < PW; kt += 32) {
        #pragma unroll
        for (int q = 0; q < 2; ++q) {
            int e = q * 256 + t;
            int row = e >> 2, seg = e & 3;
            GLL(packA + (size_t)(rb + row) * PW + kt + seg * 8, &As[e * 8]);
            GLL(packB + (size_t)(cb + row) * PW + kt + seg * 8, &Bs[e * 8]);
        }
        __syncthreads();
        s16x8 af[4], bfr[4];
        #pragma unroll
        for (int mf = 0; mf < 4; ++mf)
            af[mf] = *(const s16x8*)&As[(wm + mf * 16 + (l & 15)) * 32 + (l >> 4) * 8];
        #pragma unroll
        for (int nf = 0; nf < 4; ++nf)
            bfr[nf] = *(const s16x8*)&Bs[(wn + nf * 16 + (l & 15)) * 32 + (l >> 4) * 8];
        #pragma unroll
        for (int mf = 0; mf < 4; ++mf)
            #pragma unroll
            for (int nf = 0; nf < 4; ++nf)
                acc[mf][nf] = __builtin_amdgcn_mfma_f32_16x16x32_bf16(af[mf], bfr[nf], acc[mf][nf], 0, 0, 0);
        __syncthreads();
    }

    float fj[4], sqj[4], pj0[4], pj1[4];
    int cc[4];
    #pragma unroll
    for (int nf = 0; nf < 4; ++nf) {
        int c = cb + wn + nf * 16 + (l & 15);
        cc[nf] = c;
        fj[nf] = fbuf[c]; sqj[nf] = sqbuf[c];
        pj0[nf] = pos[2*c]; pj1[nf] = pos[2*c+1];
    }
    #pragma unroll
    for (int mf = 0; mf < 4; ++mf) {
        #pragma unroll
        for (int v = 0; v < 4; ++v) {
            int r = rb + wm + mf * 16 + ((l >> 4) << 2) + v;
            float fi = fbuf[r], sqi = sqbuf[r];
            float pi0 = pos[2*r], pi1 = pos[2*r+1];
            #pragma unroll
            for (int nf = 0; nf < 4; ++nf) {
                float d2 = __builtin_fmaxf(sqi + sqj[nf] - 2.f * (pi0 * pj0[nf] + pi1 * pj1[nf]), 0.f);
                S[(size_t)r * Nn + cc[nf]] = acc[mf][nf][v] + __expf(-0.5f * d2) + tanh_fast(fi - fj[nf]);
            }
        }
    }
}

// ---------------------------------------------------------------- k_rowstats
__global__ __launch_bounds__(256) void k_rowstats(const float* __restrict__ S,
                                                  float* __restrict__ mbuf,
                                                  float* __restrict__ lbuf) {
    int r = blockIdx.x, t = threadIdx.x;
    const float4* row = (const float4*)(S + (size_t)r * Nn);
    float4 v0 = row[t], v1 = row[t + 256], v2 = row[t + 512], v3 = row[t + 768];
    __shared__ float red[256];
    float mx = __builtin_fmaxf(
        __builtin_fmaxf(__builtin_fmaxf(__builtin_fmaxf(v0.x, v0.y), __builtin_fmaxf(v0.z, v0.w)),
                        __builtin_fmaxf(__builtin_fmaxf(v1.x, v1.y), __builtin_fmaxf(v1.z, v1.w))),
        __builtin_fmaxf(__builtin_fmaxf(__builtin_fmaxf(v2.x, v2.y), __builtin_fmaxf(v2.z, v2.w)),
                        __builtin_fmaxf(__builtin_fmaxf(v3.x, v3.y), __builtin_fmaxf(v3.z, v3.w))));
    red[t] = mx;
    __syncthreads();
    for (int s = 128; s > 0; s >>= 1) {
        if (t < s) red[t] = __builtin_fmaxf(red[t], red[t + s]);
        __syncthreads();
    }
    mx = red[0];
    __syncthreads();
    float sum = __expf(v0.x - mx) + __expf(v0.y - mx) + __expf(v0.z - mx) + __expf(v0.w - mx)
              + __expf(v1.x - mx) + __expf(v1.y - mx) + __expf(v1.z - mx) + __expf(v1.w - mx)
              + __expf(v2.x - mx) + __expf(v2.y - mx) + __expf(v2.z - mx) + __expf(v2.w - mx)
              + __expf(v3.x - mx) + __expf(v3.y - mx) + __expf(v3.z - mx) + __expf(v3.w - mx);
    red[t] = sum;
    __syncthreads();
    for (int s = 128; s > 0; s >>= 1) {
        if (t < s) red[t] += red[t + s];
        __syncthreads();
    }
    if (t == 0) { mbuf[r] = mx; lbuf[r] = 1.f / red[0]; }
}

// ---------------------------------------------------------------- k_out
__global__ __launch_bounds__(256) void k_out(float* __restrict__ S,
                                             const unsigned short* __restrict__ Vt,
                                             const float* __restrict__ mbuf,
                                             const float* __restrict__ lbuf,
                                             float* __restrict__ Opart) {
    __shared__ unsigned short As[64 * 32];
    __shared__ unsigned short Bs[256 * 32];
    __shared__ float sm[64], sl[64];
    int t = threadIdx.x;
    int w = t >> 6, l = t & 63;
    int rb = blockIdx.x * 64;
    int k0 = blockIdx.y * 1024;
    if (t < 64) { sm[t] = mbuf[rb + t]; sl[t] = lbuf[rb + t]; }
    __syncthreads();

    f32x4 acc[4][4] = {};

    for (int kt = 0; kt < 1024; kt += 32) {
        #pragma unroll
        for (int q = 0; q < 4; ++q) {
            int e = q * 256 + t;
            int row = e >> 2, seg = e & 3;
            GLL(Vt + (size_t)row * Nn + k0 + kt + seg * 8, &Bs[e * 8]);
        }
        #pragma unroll
        for (int q = 0; q < 2; ++q) {
            int e = q * 256 + t;
            int row = e >> 3, seg = e & 7;
            size_t off = (size_t)(rb + row) * Nn + k0 + kt + seg * 4;
            float4 x = *(const float4*)(S + off);
            float m = sm[row], lv = sl[row];
            x.x = __expf(x.x - m) * lv;
            x.y = __expf(x.y - m) * lv;
            x.z = __expf(x.z - m) * lv;
            x.w = __expf(x.w - m) * lv;
            *(float4*)(S + off) = x;
            u16x4v b;
            b[0] = f2bf(x.x); b[1] = f2bf(x.y); b[2] = f2bf(x.z); b[3] = f2bf(x.w);
            *(u16x4v*)&As[row * 32 + seg * 4] = b;
        }
        __syncthreads();
        s16x8 a[4];
        #pragma unroll
        for (int mf = 0; mf < 4; ++mf)
            a[mf] = *(const s16x8*)&As[(mf * 16 + (l & 15)) * 32 + (l >> 4) * 8];
        #pragma unroll
        for (int nf = 0; nf < 4; ++nf) {
            s16x8 bb = *(const s16x8*)&Bs[(w * 64 + nf * 16 + (l & 15)) * 32 + (l >> 4) * 8];
            #pragma unroll
            for (int mf = 0; mf < 4; ++mf)
                acc[mf][nf] = __builtin_amdgcn_mfma_f32_16x16x32_bf16(a[mf], bb, acc[mf][nf], 0, 0, 0);
        }
        __syncthreads();
    }
    float* dst = Opart + (size_t)blockIdx.y * Nn * Hd;
    #pragma unroll
    for (int mf = 0; mf < 4; ++mf)
        #pragma unroll
        for (int v = 0; v < 4; ++v) {
            int r = rb + mf * 16 + ((l >> 4) << 2) + v;
            #pragma unroll
            for (int nf = 0; nf < 4; ++nf) {
                int c = w * 64 + nf * 16 + (l & 15);
                dst[(size_t)r * Hd + c] = acc[mf][nf][v];
            }
        }
}

// ---------------------------------------------------------------- k_reduce
__global__ __launch_bounds__(256) void k_reduce(const float* __restrict__ P,
                                                float* __restrict__ O) {
    int id = blockIdx.x * 256 + threadIdx.x;
    size_t off = (size_t)id * 4;
    const size_t C = (size_t)Nn * Hd;
    float4 a = *(const float4*)(P + off);
    float4 b = *(const float4*)(P + C + off);
    float4 c = *(const float4*)(P + 2 * C + off);
    float4 d = *(const float4*)(P + 3 * C + off);
    float4 o;
    o.x = a.x + b.x + c.x + d.x;
    o.y = a.y + b.y + c.y + d.y;
    o.z = a.z + b.z + c.z + d.z;
    o.w = a.w + b.w + c.w + d.w;
    *(float4*)(O + off) = o;
}

// ---------------------------------------------------------------- launch
extern "C" void kernel_launch(void* const* d_in, const int* in_sizes, int n_in,
                              void* d_out, int out_size, void* d_ws, size_t ws_size,
                              hipStream_t stream) {
    const float* gene = (const float*)d_in[0];
    const float* pos  = (const float*)d_in[1];
    const float* Wq = (const float*)d_in[2];  const float* bq = (const float*)d_in[3];
    const float* Wk = (const float*)d_in[4];  const float* bk = (const float*)d_in[5];
    const float* Wv = (const float*)d_in[6];  const float* bv = (const float*)d_in[7];
    const float* Ws = (const float*)d_in[8];  const float* bs = (const float*)d_in[9];
    const float* W1 = (const float*)d_in[10]; const float* b1 = (const float*)d_in[11];
    const float* W2 = (const float*)d_in[12]; const float* b2 = (const float*)d_in[13];
    const float* Wf = (const float*)d_in[14]; const float* bf = (const float*)d_in[15];

    char* w8 = (char*)d_ws;
    // bytes: Vt [0,2M) | smalls [2M,2.125M) | packA [2.125M,8.4M) | packB
    // [8.4M,14.8M) | geneh [14.8M,19M) | Wt [19M,19.79M) | W1t/W2t [19.79M,20.05M)
    // Opart (16.77MB) aliases packA+packB+geneh (all dead by k_out).
    unsigned short* Vt    = (unsigned short*)w8;                      // [256][4096]
    float*  fbuf  = (float*)(w8 + 2097152);
    float*  sqbuf = fbuf + Nn;
    float*  rinvb = sqbuf + Nn;
    float*  mbuf  = rinvb + Nn;
    float*  lbuf  = mbuf + Nn;
    unsigned short* packA = (unsigned short*)(w8 + 2228224);          // [4096][768]
    unsigned short* packB = (unsigned short*)(w8 + 8519680);          // [4096][768]
    unsigned short* geneh = (unsigned short*)(w8 + 14811136);         // [4096][512]
    unsigned short* Wt    = (unsigned short*)(w8 + 19005440);         // [768][512]
    unsigned short* W1t   = (unsigned short*)(w8 + 19791872);         // [256][256]
    unsigned short* W2t   = (unsigned short*)(w8 + 19922944);         // [256][256]
    float*  Opart = (float*)(w8 + 2228224);                           // [4][4096][256]

    float* S = (float*)d_out;                      // [N][N] attention weights
    float* O = S + (size_t)Nn * Nn;                // [N][256]

    k_norm<<<Nn, 64, 0, stream>>>(gene, pos, rinvb, sqbuf);
    k_wt<<<dim3(Gd / 64, PW / 64), 256, 0, stream>>>(Wq, Wk, Wv, Wt);
    k_wt2<<<dim3(Hd / 64, 8), 256, 0, stream>>>(W1, W2, W1t, W2t);
    k_mlp_mfma<<<Nn / 16, 256, 0, stream>>>(pos, Ws, bs, W1t, b1, W2t, b2, Wf, bf, fbuf);
    k_pack<<<(Nn * (Gd / 4)) / 256, 256, 0, stream>>>(gene, rinvb, packA, packB, geneh);
    k_qkv_mfma<<<dim3(Nn / 64, 6), 256, 0, stream>>>(geneh, Wt, bq, bk, bv,
                                                     packA, packB, Vt);
    k_logits<<<dim3(Nn / 128, Nn / 128), 256, 0, stream>>>(packA, packB, pos,
                                                           fbuf, sqbuf, S);
    k_rowstats<<<Nn, 256, 0, stream>>>(S, mbuf, lbuf);
    k_out<<<dim3(Nn / 64, 4), 256, 0, stream>>>(S, Vt, mbuf, lbuf, Opart);
    k_reduce<<<(Nn * Hd / 4) / 256, 256, 0, stream>>>(Opart, O);
}

// Round 10
// 238.235 us; speedup vs baseline: 3.5831x; 1.0369x over previous
//
#include <hip/hip_runtime.h>

#define Nn 4096
#define Gd 512
#define Hd 256
#define PW 768   // packed operand width: 256 (Q or K) + 512 (normalized gene)

typedef float f32x4 __attribute__((ext_vector_type(4)));
typedef short s16x8 __attribute__((ext_vector_type(8)));
typedef _Float16 f16x8 __attribute__((ext_vector_type(8)));
typedef unsigned short u16x4v __attribute__((ext_vector_type(4)));
typedef unsigned short u16x8v __attribute__((ext_vector_type(8)));

// async global->LDS, 16B per lane; LDS dest must be wave-uniform base + lane*16.
#define GLL(gp, lp) __builtin_amdgcn_global_load_lds((const __attribute__((address_space(1))) void*)(gp), (__attribute__((address_space(3))) void*)(lp), 16, 0, 0)

// fp32 -> bf16 bits, round-to-nearest-even (integer path; no __bf16 types)
__device__ inline unsigned short f2bf(float x) {
    unsigned u = __builtin_bit_cast(unsigned, x);
    return (unsigned short)((u + 0x7FFFu + ((u >> 16) & 1u)) >> 16);
}
// fp32 -> fp16 bits
__device__ inline unsigned short f2h(float x) {
    return __builtin_bit_cast(unsigned short, (_Float16)x);
}

__device__ inline float tanh_fast(float x) {
    x = __builtin_fminf(__builtin_fmaxf(x, -15.f), 15.f);
    float e2 = __expf(2.f * x);
    return (e2 - 1.f) / (e2 + 1.f);
}

// ---------------------------------------------------------------- k_norm
__global__ __launch_bounds__(64) void k_norm(const float* __restrict__ gene,
                                             const float* __restrict__ pos,
                                             float* __restrict__ rinvb,
                                             float* __restrict__ sqbuf) {
    int i = blockIdx.x, t = threadIdx.x;
    const float4* gr = (const float4*)(gene + (size_t)i * Gd);
    float4 a = gr[t], b = gr[t + 64];
    float ss = a.x*a.x + a.y*a.y + a.z*a.z + a.w*a.w
             + b.x*b.x + b.y*b.y + b.z*b.z + b.w*b.w;
    #pragma unroll
    for (int m = 1; m < 64; m <<= 1) ss += __shfl_xor(ss, m, 64);
    if (t == 0) {
        rinvb[i] = 1.f / __builtin_fmaxf(__builtin_sqrtf(ss), 1e-12f);
        float p0 = pos[2*i], p1 = pos[2*i+1];
        sqbuf[i] = p0*p0 + p1*p1;
    }
}

// ---------------------------------------------------------------- k_wt
// Wt[768][512] fp16: rows 0-255 = Wq^T, 256-511 = Wk^T, 512-767 = Wv^T.
__global__ __launch_bounds__(256) void k_wt(const float* __restrict__ Wq,
                                            const float* __restrict__ Wk,
                                            const float* __restrict__ Wv,
                                            unsigned short* __restrict__ Wt) {
    __shared__ float tile[64][65];
    int t = threadIdx.x;
    int kb = blockIdx.x * 64;
    int by = blockIdx.y;
    int mid = by >> 2;
    int cb2 = (by & 3) * 64;
    const float* W = (mid == 0) ? Wq : (mid == 1) ? Wk : Wv;
    #pragma unroll
    for (int q = 0; q < 16; ++q) {
        int idx = q * 256 + t;
        int row = idx >> 6, col = idx & 63;
        tile[row][col] = W[(size_t)(kb + row) * Hd + cb2 + col];
    }
    __syncthreads();
    int crow = by * 64;
    #pragma unroll
    for (int q = 0; q < 16; ++q) {
        int idx = q * 256 + t;
        int c = idx >> 6, k = idx & 63;
        Wt[(size_t)(crow + c) * Gd + kb + k] = f2h(tile[k][c]);
    }
}

// ---------------------------------------------------------------- k_wt2
__global__ __launch_bounds__(256) void k_wt2(const float* __restrict__ W1,
                                             const float* __restrict__ W2,
                                             unsigned short* __restrict__ W1t,
                                             unsigned short* __restrict__ W2t) {
    __shared__ float tile[64][65];
    int t = threadIdx.x;
    int kb = blockIdx.x * 64;
    int by = blockIdx.y;
    int mid = by >> 2;
    int cb2 = (by & 3) * 64;
    const float* W = (mid == 0) ? W1 : W2;
    unsigned short* Wo = (mid == 0) ? W1t : W2t;
    #pragma unroll
    for (int q = 0; q < 16; ++q) {
        int idx = q * 256 + t;
        int row = idx >> 6, col = idx & 63;
        tile[row][col] = W[(size_t)(kb + row) * Hd + cb2 + col];
    }
    __syncthreads();
    #pragma unroll
    for (int q = 0; q < 16; ++q) {
        int idx = q * 256 + t;
        int c = idx >> 6, k = idx & 63;
        Wo[(size_t)(cb2 + c) * Hd + kb + k] = f2h(tile[k][c]);
    }
}

// ---------------------------------------------------------------- k_mlp_mfma
__global__ __launch_bounds__(256) void k_mlp_mfma(const float* __restrict__ pos,
                                                  const float* __restrict__ Ws, const float* __restrict__ bs,
                                                  const unsigned short* __restrict__ W1t, const float* __restrict__ b1,
                                                  const unsigned short* __restrict__ W2t, const float* __restrict__ b2,
                                                  const float* __restrict__ Wf, const float* __restrict__ bf,
                                                  float* __restrict__ fbuf) {
    __shared__ unsigned short A_lds[16 * 256];
    __shared__ unsigned short H_lds[16 * 256];
    __shared__ unsigned short Bs_[256 * 32];
    __shared__ float E_lds[16][256];
    __shared__ float sp_[32];
    int t = threadIdx.x;
    int w = t >> 6, l = t & 63;
    int rb = blockIdx.x * 16;
    if (t < 32) sp_[t] = pos[rb * 2 + t];
    __syncthreads();
    #pragma unroll
    for (int q = 0; q < 16; ++q) {
        float v = sp_[2*q] * Ws[t] + sp_[2*q+1] * Ws[Hd + t] + bs[t];
        A_lds[q * 256 + t] = f2h(v);
    }
    __syncthreads();

    f32x4 acc[4] = {};
    for (int kt = 0; kt < Hd; kt += 32) {
        #pragma unroll
        for (int q = 0; q < 4; ++q) {
            int e = q * 256 + t;
            int row = e >> 2, seg = e & 3;
            GLL(W1t + (size_t)row * Hd + kt + seg * 8, &Bs_[e * 8]);
        }
        __syncthreads();
        f16x8 af = *(const f16x8*)&A_lds[(l & 15) * 256 + kt + (l >> 4) * 8];
        #pragma unroll
        for (int nf = 0; nf < 4; ++nf) {
            f16x8 bb = *(const f16x8*)&Bs_[(w * 64 + nf * 16 + (l & 15)) * 32 + (l >> 4) * 8];
            acc[nf] = __builtin_amdgcn_mfma_f32_16x16x32_f16(af, bb, acc[nf], 0, 0, 0);
        }
        __syncthreads();
    }
    #pragma unroll
    for (int nf = 0; nf < 4; ++nf) {
        int c = w * 64 + nf * 16 + (l & 15);
        float bb = b1[c];
        #pragma unroll
        for (int v = 0; v < 4; ++v) {
            int r = ((l >> 4) << 2) + v;
            H_lds[r * 256 + c] = f2h(tanh_fast(acc[nf][v] + bb));
        }
    }
    __syncthreads();

    f32x4 acc2[4] = {};
    for (int kt = 0; kt < Hd; kt += 32) {
        #pragma unroll
        for (int q = 0; q < 4; ++q) {
            int e = q * 256 + t;
            int row = e >> 2, seg = e & 3;
            GLL(W2t + (size_t)row * Hd + kt + seg * 8, &Bs_[e * 8]);
        }
        __syncthreads();
        f16x8 af = *(const f16x8*)&H_lds[(l & 15) * 256 + kt + (l >> 4) * 8];
        #pragma unroll
        for (int nf = 0; nf < 4; ++nf) {
            f16x8 bb = *(const f16x8*)&Bs_[(w * 64 + nf * 16 + (l & 15)) * 32 + (l >> 4) * 8];
            acc2[nf] = __builtin_amdgcn_mfma_f32_16x16x32_f16(af, bb, acc2[nf], 0, 0, 0);
        }
        __syncthreads();
    }
    #pragma unroll
    for (int nf = 0; nf < 4; ++nf) {
        int c = w * 64 + nf * 16 + (l & 15);
        float bb = b2[c];
        #pragma unroll
        for (int v = 0; v < 4; ++v)
            E_lds[((l >> 4) << 2) + v][c] = __builtin_fmaxf(acc2[nf][v] + bb, 0.f);
    }
    __syncthreads();

    f32x4 wf4 = *(const f32x4*)&Wf[l * 4];
    #pragma unroll
    for (int rr = 0; rr < 4; ++rr) {
        int r = w * 4 + rr;
        f32x4 ev = *(const f32x4*)&E_lds[r][l * 4];
        float s = ev[0]*wf4[0] + ev[1]*wf4[1] + ev[2]*wf4[2] + ev[3]*wf4[3];
        #pragma unroll
        for (int m = 1; m < 64; m <<= 1) s += __shfl_xor(s, m, 64);
        if (l == 0) fbuf[rb + r] = s + bf[0];
    }
}

// ---------------------------------------------------------------- k_pack
__global__ __launch_bounds__(256) void k_pack(const float* __restrict__ gene,
                                              const float* __restrict__ rinvb,
                                              unsigned short* __restrict__ packA,
                                              unsigned short* __restrict__ packB,
                                              unsigned short* __restrict__ geneh) {
    int id = blockIdx.x * 256 + threadIdx.x;
    int row = id >> 7;
    int c4 = (id & 127) << 2;
    float ri = rinvb[row];
    float4 v = *(const float4*)(gene + (size_t)row * Gd + c4);
    u16x4v h;
    h[0] = f2h(v.x); h[1] = f2h(v.y); h[2] = f2h(v.z); h[3] = f2h(v.w);
    *(u16x4v*)(geneh + (size_t)row * Gd + c4) = h;
    u16x4v b;
    b[0] = f2bf(v.x * ri); b[1] = f2bf(v.y * ri);
    b[2] = f2bf(v.z * ri); b[3] = f2bf(v.w * ri);
    *(u16x4v*)(packA + (size_t)row * PW + Hd + c4) = b;
    *(u16x4v*)(packB + (size_t)row * PW + Hd + c4) = b;
}

// ---------------------------------------------------------------- k_qkv_mfma
__global__ __launch_bounds__(256) void k_qkv_mfma(const unsigned short* __restrict__ geneh,
                                                  const unsigned short* __restrict__ Wt,
                                                  const float* __restrict__ bq,
                                                  const float* __restrict__ bk,
                                                  const float* __restrict__ bv,
                                                  unsigned short* __restrict__ packA,
                                                  unsigned short* __restrict__ packB,
                                                  unsigned short* __restrict__ Vt) {
    __shared__ unsigned short As[64 * 32];
    __shared__ unsigned short Bs[128 * 32];
    int t = threadIdx.x;
    int w = t >> 6, l = t & 63;
    int wm = (w >> 1) * 32, wn = (w & 1) * 64;
    int rb = blockIdx.x * 64;
    int cb = blockIdx.y * 128;
    int mid = blockIdx.y >> 1;
    const float* bia = (mid == 0) ? bq : (mid == 1) ? bk : bv;

    f32x4 acc[2][4] = {};

    for (int kt = 0; kt < Gd; kt += 32) {
        {
            int row = t >> 2, seg = t & 3;
            GLL(geneh + (size_t)(rb + row) * Gd + kt + seg * 8, &As[t * 8]);
        }
        #pragma unroll
        for (int q = 0; q < 2; ++q) {
            int e = q * 256 + t;
            int row = e >> 2, seg = e & 3;
            GLL(Wt + (size_t)(cb + row) * Gd + kt + seg * 8, &Bs[e * 8]);
        }
        __syncthreads();
        f16x8 af[2], bfr[4];
        #pragma unroll
        for (int mf = 0; mf < 2; ++mf)
            af[mf] = *(const f16x8*)&As[(wm + mf * 16 + (l & 15)) * 32 + (l >> 4) * 8];
        #pragma unroll
        for (int nf = 0; nf < 4; ++nf)
            bfr[nf] = *(const f16x8*)&Bs[(wn + nf * 16 + (l & 15)) * 32 + (l >> 4) * 8];
        #pragma unroll
        for (int mf = 0; mf < 2; ++mf)
            #pragma unroll
            for (int nf = 0; nf < 4; ++nf)
                acc[mf][nf] = __builtin_amdgcn_mfma_f32_16x16x32_f16(af[mf], bfr[nf], acc[mf][nf], 0, 0, 0);
        __syncthreads();
    }

    float scale = (mid == 0) ? 0.0625f : 1.f;
    #pragma unroll
    for (int nf = 0; nf < 4; ++nf) {
        int cg = cb + wn + nf * 16 + (l & 15);
        int cloc = cg - mid * 256;
        float bb = bia[cloc];
        #pragma unroll
        for (int mf = 0; mf < 2; ++mf) {
            int r0 = rb + wm + mf * 16 + ((l >> 4) << 2);
            if (mid == 2) {
                u16x4v o;
                #pragma unroll
                for (int v = 0; v < 4; ++v) o[v] = f2bf(acc[mf][nf][v] + bb);
                *(u16x4v*)(Vt + (size_t)cloc * Nn + r0) = o;
            } else {
                unsigned short* dst = (mid == 0) ? packA : packB;
                #pragma unroll
                for (int v = 0; v < 4; ++v)
                    dst[(size_t)(r0 + v) * PW + cloc] = f2bf((acc[mf][nf][v] + bb) * scale);
            }
        }
    }
}

// ---------------------------------------------------------------- k_logits
// Swapped-operand MFMA: acc[cf][rf] = mfma(bfr[cf], af[rf], .) so each lane
// holds 4 CONSECUTIVE S-columns at a fixed S-row -> float4 stores.
// Also emits per-(row, 64-col-chunk) partial max / sumexp for softmax stats.
__global__ __launch_bounds__(256) void k_logits(const unsigned short* __restrict__ packA,
                                                const unsigned short* __restrict__ packB,
                                                const float* __restrict__ pos,
                                                const float* __restrict__ fbuf,
                                                const float* __restrict__ sqbuf,
                                                float* __restrict__ S,
                                                float* __restrict__ pmaxb,
                                                float* __restrict__ psumb) {
    __shared__ unsigned short As[128 * 32];
    __shared__ unsigned short Bs[128 * 32];
    int t = threadIdx.x;
    int w = t >> 6, l = t & 63;
    int wr = (w >> 1) * 64, wc = (w & 1) * 64;
    int rb = blockIdx.x * 128, cb = blockIdx.y * 128;

    f32x4 acc[4][4] = {};   // [cf][rf]

    for (int kt = 0; kt < PW; kt += 32) {
        #pragma unroll
        for (int q = 0; q < 2; ++q) {
            int e = q * 256 + t;
            int row = e >> 2, seg = e & 3;
            GLL(packA + (size_t)(rb + row) * PW + kt + seg * 8, &As[e * 8]);
            GLL(packB + (size_t)(cb + row) * PW + kt + seg * 8, &Bs[e * 8]);
        }
        __syncthreads();
        s16x8 af[4], bfr[4];
        #pragma unroll
        for (int rf = 0; rf < 4; ++rf)
            af[rf] = *(const s16x8*)&As[(wr + rf * 16 + (l & 15)) * 32 + (l >> 4) * 8];
        #pragma unroll
        for (int cf = 0; cf < 4; ++cf)
            bfr[cf] = *(const s16x8*)&Bs[(wc + cf * 16 + (l & 15)) * 32 + (l >> 4) * 8];
        #pragma unroll
        for (int cf = 0; cf < 4; ++cf)
            #pragma unroll
            for (int rf = 0; rf < 4; ++rf)
                acc[cf][rf] = __builtin_amdgcn_mfma_f32_16x16x32_bf16(bfr[cf], af[rf], acc[cf][rf], 0, 0, 0);
        __syncthreads();
    }

    // epilogue: D-col (l&15) = S-row, D-row ((l>>4)*4+v) = S-col
    int lv = (l >> 4) << 2;
    #pragma unroll
    for (int rf = 0; rf < 4; ++rf) {
        int r = rb + wr + rf * 16 + (l & 15);
        float fi = fbuf[r], sqi = sqbuf[r];
        float pi0 = pos[2*r], pi1 = pos[2*r+1];
        f32x4 outs[4];
        #pragma unroll
        for (int cf = 0; cf < 4; ++cf) {
            int c0 = cb + wc + cf * 16 + lv;
            f32x4 fj  = *(const f32x4*)(fbuf + c0);
            f32x4 sqj = *(const f32x4*)(sqbuf + c0);
            f32x4 p01 = *(const f32x4*)(pos + 2 * c0);
            f32x4 p23 = *(const f32x4*)(pos + 2 * c0 + 4);
            float pj0[4] = {p01[0], p01[2], p23[0], p23[2]};
            float pj1[4] = {p01[1], p01[3], p23[1], p23[3]};
            f32x4 o;
            #pragma unroll
            for (int v = 0; v < 4; ++v) {
                float d2 = __builtin_fmaxf(sqi + sqj[v] - 2.f * (pi0 * pj0[v] + pi1 * pj1[v]), 0.f);
                o[v] = acc[cf][rf][v] + __expf(-0.5f * d2) + tanh_fast(fi - fj[v]);
            }
            outs[cf] = o;
            *(f32x4*)(S + (size_t)r * Nn + c0) = o;
        }
        // partial row stats over this wave's 64 cols
        float mx = -3.4e38f;
        #pragma unroll
        for (int cf = 0; cf < 4; ++cf)
            #pragma unroll
            for (int v = 0; v < 4; ++v) mx = __builtin_fmaxf(mx, outs[cf][v]);
        mx = __builtin_fmaxf(mx, __shfl_xor(mx, 16));
        mx = __builtin_fmaxf(mx, __shfl_xor(mx, 32));
        float s = 0.f;
        #pragma unroll
        for (int cf = 0; cf < 4; ++cf)
            #pragma unroll
            for (int v = 0; v < 4; ++v) s += __expf(outs[cf][v] - mx);
        s += __shfl_xor(s, 16);
        s += __shfl_xor(s, 32);
        if (l < 16) {
            int chunk = blockIdx.y * 2 + (w & 1);
            pmaxb[(size_t)r * 64 + chunk] = mx;
            psumb[(size_t)r * 64 + chunk] = s;
        }
    }
}

// ---------------------------------------------------------------- k_rowstats2
// combine 64 per-chunk partials per row -> global max + 1/sumexp
__global__ __launch_bounds__(256) void k_rowstats2(const float* __restrict__ pmaxb,
                                                   const float* __restrict__ psumb,
                                                   float* __restrict__ mbuf,
                                                   float* __restrict__ lbuf) {
    int r = blockIdx.x * 256 + threadIdx.x;
    const f32x4* pm = (const f32x4*)(pmaxb + (size_t)r * 64);
    const f32x4* ps = (const f32x4*)(psumb + (size_t)r * 64);
    float m = -3.4e38f;
    #pragma unroll
    for (int i = 0; i < 16; ++i) {
        f32x4 v = pm[i];
        m = __builtin_fmaxf(m, __builtin_fmaxf(__builtin_fmaxf(v[0], v[1]),
                                               __builtin_fmaxf(v[2], v[3])));
    }
    float s = 0.f;
    #pragma unroll
    for (int i = 0; i < 16; ++i) {
        f32x4 v = pm[i], u = ps[i];
        s += u[0] * __expf(v[0] - m) + u[1] * __expf(v[1] - m)
           + u[2] * __expf(v[2] - m) + u[3] * __expf(v[3] - m);
    }
    mbuf[r] = m;
    lbuf[r] = 1.f / s;
}

// ---------------------------------------------------------------- k_out
// 32-row tiles (grid 128 x 4 = 512 blocks, 2/CU) for occupancy.
__global__ __launch_bounds__(256) void k_out(float* __restrict__ S,
                                             const unsigned short* __restrict__ Vt,
                                             const float* __restrict__ mbuf,
                                             const float* __restrict__ lbuf,
                                             float* __restrict__ Opart) {
    __shared__ unsigned short As[32 * 32];
    __shared__ unsigned short Bs[256 * 32];
    __shared__ float sm[32], sl[32];
    int t = threadIdx.x;
    int w = t >> 6, l = t & 63;
    int rb = blockIdx.x * 32;
    int k0 = blockIdx.y * 1024;
    if (t < 32) { sm[t] = mbuf[rb + t]; sl[t] = lbuf[rb + t]; }
    __syncthreads();

    f32x4 acc[2][4] = {};

    for (int kt = 0; kt < 1024; kt += 32) {
        // B: 256 Vt rows x 32 k = 16KB -> 1024 GLL issues
        #pragma unroll
        for (int q = 0; q < 4; ++q) {
            int e = q * 256 + t;
            int row = e >> 2, seg = e & 3;
            GLL(Vt + (size_t)row * Nn + k0 + kt + seg * 8, &Bs[e * 8]);
        }
        // A: 32 rows x 32 k: normalize raw logits -> weights -> bf16 LDS
        {
            int row = t >> 3, seg = t & 7;
            size_t off = (size_t)(rb + row) * Nn + k0 + kt + seg * 4;
            float4 x = *(const float4*)(S + off);
            float m = sm[row], lv = sl[row];
            x.x = __expf(x.x - m) * lv;
            x.y = __expf(x.y - m) * lv;
            x.z = __expf(x.z - m) * lv;
            x.w = __expf(x.w - m) * lv;
            *(float4*)(S + off) = x;
            u16x4v b;
            b[0] = f2bf(x.x); b[1] = f2bf(x.y); b[2] = f2bf(x.z); b[3] = f2bf(x.w);
            *(u16x4v*)&As[row * 32 + seg * 4] = b;
        }
        __syncthreads();
        s16x8 a[2];
        #pragma unroll
        for (int mf = 0; mf < 2; ++mf)
            a[mf] = *(const s16x8*)&As[(mf * 16 + (l & 15)) * 32 + (l >> 4) * 8];
        #pragma unroll
        for (int nf = 0; nf < 4; ++nf) {
            s16x8 bb = *(const s16x8*)&Bs[(w * 64 + nf * 16 + (l & 15)) * 32 + (l >> 4) * 8];
            #pragma unroll
            for (int mf = 0; mf < 2; ++mf)
                acc[mf][nf] = __builtin_amdgcn_mfma_f32_16x16x32_bf16(a[mf], bb, acc[mf][nf], 0, 0, 0);
        }
        __syncthreads();
    }
    float* dst = Opart + (size_t)blockIdx.y * Nn * Hd;
    #pragma unroll
    for (int mf = 0; mf < 2; ++mf)
        #pragma unroll
        for (int v = 0; v < 4; ++v) {
            int r = rb + mf * 16 + ((l >> 4) << 2) + v;
            #pragma unroll
            for (int nf = 0; nf < 4; ++nf) {
                int c = w * 64 + nf * 16 + (l & 15);
                dst[(size_t)r * Hd + c] = acc[mf][nf][v];
            }
        }
}

// ---------------------------------------------------------------- k_reduce
__global__ __launch_bounds__(256) void k_reduce(const float* __restrict__ P,
                                                float* __restrict__ O) {
    int id = blockIdx.x * 256 + threadIdx.x;
    size_t off = (size_t)id * 4;
    const size_t C = (size_t)Nn * Hd;
    float4 a = *(const float4*)(P + off);
    float4 b = *(const float4*)(P + C + off);
    float4 c = *(const float4*)(P + 2 * C + off);
    float4 d = *(const float4*)(P + 3 * C + off);
    float4 o;
    o.x = a.x + b.x + c.x + d.x;
    o.y = a.y + b.y + c.y + d.y;
    o.z = a.z + b.z + c.z + d.z;
    o.w = a.w + b.w + c.w + d.w;
    *(float4*)(O + off) = o;
}

// ---------------------------------------------------------------- launch
extern "C" void kernel_launch(void* const* d_in, const int* in_sizes, int n_in,
                              void* d_out, int out_size, void* d_ws, size_t ws_size,
                              hipStream_t stream) {
    const float* gene = (const float*)d_in[0];
    const float* pos  = (const float*)d_in[1];
    const float* Wq = (const float*)d_in[2];  const float* bq = (const float*)d_in[3];
    const float* Wk = (const float*)d_in[4];  const float* bk = (const float*)d_in[5];
    const float* Wv = (const float*)d_in[6];  const float* bv = (const float*)d_in[7];
    const float* Ws = (const float*)d_in[8];  const float* bs = (const float*)d_in[9];
    const float* W1 = (const float*)d_in[10]; const float* b1 = (const float*)d_in[11];
    const float* W2 = (const float*)d_in[12]; const float* b2 = (const float*)d_in[13];
    const float* Wf = (const float*)d_in[14]; const float* bf = (const float*)d_in[15];

    char* w8 = (char*)d_ws;
    // bytes: Vt [0,2M) | smalls [2M,2.125M) | packA [2.125M,8.4M) | packB
    // [8.4M,14.8M) | geneh [14.8M,19M) | Wt [19M,19.79M) | W1t/W2t [19.79M,20.05M)
    // pmax/psum (2MB) alias geneh (dead after k_qkv_mfma);
    // Opart (16.77MB) aliases packA+packB+geneh (all dead by k_out).
    unsigned short* Vt    = (unsigned short*)w8;                      // [256][4096]
    float*  fbuf  = (float*)(w8 + 2097152);
    float*  sqbuf = fbuf + Nn;
    float*  rinvb = sqbuf + Nn;
    float*  mbuf  = rinvb + Nn;
    float*  lbuf  = mbuf + Nn;
    unsigned short* packA = (unsigned short*)(w8 + 2228224);          // [4096][768]
    unsigned short* packB = (unsigned short*)(w8 + 8519680);          // [4096][768]
    unsigned short* geneh = (unsigned short*)(w8 + 14811136);         // [4096][512]
    unsigned short* Wt    = (unsigned short*)(w8 + 19005440);         // [768][512]
    unsigned short* W1t   = (unsigned short*)(w8 + 19791872);         // [256][256]
    unsigned short* W2t   = (unsigned short*)(w8 + 19922944);         // [256][256]
    float*  pmaxb = (float*)(w8 + 14811136);                          // [4096][64]
    float*  psumb = (float*)(w8 + 14811136 + 1048576);                // [4096][64]
    float*  Opart = (float*)(w8 + 2228224);                           // [4][4096][256]

    float* S = (float*)d_out;                      // [N][N] attention weights
    float* O = S + (size_t)Nn * Nn;                // [N][256]

    k_norm<<<Nn, 64, 0, stream>>>(gene, pos, rinvb, sqbuf);
    k_wt<<<dim3(Gd / 64, PW / 64), 256, 0, stream>>>(Wq, Wk, Wv, Wt);
    k_wt2<<<dim3(Hd / 64, 8), 256, 0, stream>>>(W1, W2, W1t, W2t);
    k_mlp_mfma<<<Nn / 16, 256, 0, stream>>>(pos, Ws, bs, W1t, b1, W2t, b2, Wf, bf, fbuf);
    k_pack<<<(Nn * (Gd / 4)) / 256, 256, 0, stream>>>(gene, rinvb, packA, packB, geneh);
    k_qkv_mfma<<<dim3(Nn / 64, 6), 256, 0, stream>>>(geneh, Wt, bq, bk, bv,
                                                     packA, packB, Vt);
    k_logits<<<dim3(Nn / 128, Nn / 128), 256, 0, stream>>>(packA, packB, pos,
                                                           fbuf, sqbuf, S, pmaxb, psumb);
    k_rowstats2<<<Nn / 256, 256, 0, stream>>>(pmaxb, psumb, mbuf, lbuf);
    k_out<<<dim3(Nn / 32, 4), 256, 0, stream>>>(S, Vt, mbuf, lbuf, Opart);
    k_reduce<<<(Nn * Hd / 4) / 256, 256, 0, stream>>>(Opart, O);
}